// Round 1
// baseline (247.921 us; speedup 1.0000x reference)
//
#include <hip/hip_runtime.h>
#include <hip/hip_bf16.h>

// Non-local block via rank-128 factorization (no 256x256 Gram):
//   G~ = g_w x + g_b ; T~ = theta_w x + theta_b ; P~ = phi_w x + phi_b   [128x4096]/batch
//   S''[p][g] = sum_n P~[p][n] G~[g][n]                                  [128x128]/batch
//   W2 = out_w @ S''^T / N                                               [256x128]/batch
//   out = x + W2 @ T~ + out_b
// 4 launches:
//  kA: x -> bf16 XT [n][c] transpose (LDS) + weight stack bf16 + out_w bf16 + biases
//  kB: projections [384x4096] = Wst @ XT^T(+bias); P,G -> PG rows; T -> TT transposed
//  kC: S'' (K=4096, 2-deep prefetch) -> LDS bf16 ; W2 = out_w @ S''(_bt) -> bf16
//  kD: out = x + W2 @ TT(_bt) + out_b

#define CC   256
#define NSP  4096
#define NB   4

typedef __attribute__((ext_vector_type(8))) short bf16x8;
typedef __attribute__((ext_vector_type(4))) float f32x4;

// fp32 region (float offsets from wsf)
#define F_BST  0                    // [384] biases (g,theta,phi)
// bf16 region (ushort offsets from wsh = wsf + 512)
#define H_XT   0                    // [4][4096][256]
#define H_PG   4194304              // [4][256][4096]  rows 0-127 = G~, 128-255 = P~
#define H_TT   8388608              // [4][4096][128]  TT[n][p] = T~[p][n]
#define H_WST  10485760             // [384][256]  rows: g_w / theta_w / phi_w
#define H_OWH  10584064             // [256][128]  out_w bf16
#define H_W2   10616832             // [4][256][128]

__device__ __forceinline__ unsigned short f2bf(float f) {
  __hip_bfloat16 h = __float2bfloat16(f);
  return __builtin_bit_cast(unsigned short, h);
}
__device__ __forceinline__ uint4 pack8(const unsigned short* h) {
  uint4 u;
  u.x = (unsigned)h[0] | ((unsigned)h[1] << 16);
  u.y = (unsigned)h[2] | ((unsigned)h[3] << 16);
  u.z = (unsigned)h[4] | ((unsigned)h[5] << 16);
  u.w = (unsigned)h[6] | ((unsigned)h[7] << 16);
  return u;
}

// Wave computes C[64x64] += A[64xK] * B^T[64xK] (bf16 row-major, K contiguous), 1-deep prefetch.
__device__ __forceinline__ void wave_gemm_bt(const unsigned short* __restrict__ A, int pitchA,
                                             const unsigned short* __restrict__ B, int pitchB,
                                             int K, int lane, f32x4 acc[4][4]) {
  int lm = lane & 15, lq = lane >> 4;
  const unsigned short* ap[4];
  const unsigned short* bp[4];
#pragma unroll
  for (int i = 0; i < 4; ++i) {
    ap[i] = A + (size_t)(i * 16 + lm) * pitchA + lq * 8;
    bp[i] = B + (size_t)(i * 16 + lm) * pitchB + lq * 8;
  }
  bf16x8 a0[4], b0[4];
#pragma unroll
  for (int i = 0; i < 4; ++i) {
    a0[i] = *(const bf16x8*)(ap[i]);
    b0[i] = *(const bf16x8*)(bp[i]);
  }
  for (int k = 32; k < K; k += 32) {
    bf16x8 a1[4], b1[4];
#pragma unroll
    for (int i = 0; i < 4; ++i) {
      a1[i] = *(const bf16x8*)(ap[i] + k);
      b1[i] = *(const bf16x8*)(bp[i] + k);
    }
#pragma unroll
    for (int mi = 0; mi < 4; ++mi)
#pragma unroll
      for (int ni = 0; ni < 4; ++ni)
        acc[mi][ni] = __builtin_amdgcn_mfma_f32_16x16x32_bf16(a0[mi], b0[ni], acc[mi][ni], 0, 0, 0);
#pragma unroll
    for (int i = 0; i < 4; ++i) { a0[i] = a1[i]; b0[i] = b1[i]; }
  }
#pragma unroll
  for (int mi = 0; mi < 4; ++mi)
#pragma unroll
    for (int ni = 0; ni < 4; ++ni)
      acc[mi][ni] = __builtin_amdgcn_mfma_f32_16x16x32_bf16(a0[mi], b0[ni], acc[mi][ni], 0, 0, 0);
}

// 2-deep prefetch variant for long-K, low-occupancy use (kC). K >= 64, K % 32 == 0.
__device__ __forceinline__ void wave_gemm_bt2(const unsigned short* __restrict__ A, int pitchA,
                                              const unsigned short* __restrict__ B, int pitchB,
                                              int K, int lane, f32x4 acc[4][4]) {
  int lm = lane & 15, lq = lane >> 4;
  const unsigned short* ap[4];
  const unsigned short* bp[4];
#pragma unroll
  for (int i = 0; i < 4; ++i) {
    ap[i] = A + (size_t)(i * 16 + lm) * pitchA + lq * 8;
    bp[i] = B + (size_t)(i * 16 + lm) * pitchB + lq * 8;
  }
  bf16x8 a0[4], b0[4], a1[4], b1[4];
#pragma unroll
  for (int i = 0; i < 4; ++i) { a0[i] = *(const bf16x8*)(ap[i]);      b0[i] = *(const bf16x8*)(bp[i]); }
#pragma unroll
  for (int i = 0; i < 4; ++i) { a1[i] = *(const bf16x8*)(ap[i] + 32); b1[i] = *(const bf16x8*)(bp[i] + 32); }
  for (int k = 64; k < K; k += 32) {
    bf16x8 a2[4], b2[4];
#pragma unroll
    for (int i = 0; i < 4; ++i) {
      a2[i] = *(const bf16x8*)(ap[i] + k);
      b2[i] = *(const bf16x8*)(bp[i] + k);
    }
#pragma unroll
    for (int mi = 0; mi < 4; ++mi)
#pragma unroll
      for (int ni = 0; ni < 4; ++ni)
        acc[mi][ni] = __builtin_amdgcn_mfma_f32_16x16x32_bf16(a0[mi], b0[ni], acc[mi][ni], 0, 0, 0);
#pragma unroll
    for (int i = 0; i < 4; ++i) { a0[i] = a1[i]; b0[i] = b1[i]; a1[i] = a2[i]; b1[i] = b2[i]; }
  }
#pragma unroll
  for (int mi = 0; mi < 4; ++mi)
#pragma unroll
    for (int ni = 0; ni < 4; ++ni)
      acc[mi][ni] = __builtin_amdgcn_mfma_f32_16x16x32_bf16(a0[mi], b0[ni], acc[mi][ni], 0, 0, 0);
#pragma unroll
  for (int mi = 0; mi < 4; ++mi)
#pragma unroll
    for (int ni = 0; ni < 4; ++ni)
      acc[mi][ni] = __builtin_amdgcn_mfma_f32_16x16x32_bf16(a1[mi], b1[ni], acc[mi][ni], 0, 0, 0);
}

// ---- kA: XT transpose (x fp32 -> bf16 [n][c]) + weight stack + out_w bf16 + biases ----
__global__ __launch_bounds__(256) void kA(
    const float* __restrict__ g_w, const float* __restrict__ theta_w,
    const float* __restrict__ phi_w, const float* __restrict__ out_w,
    const float* __restrict__ g_b, const float* __restrict__ theta_b,
    const float* __restrict__ phi_b, const float* __restrict__ x,
    float* __restrict__ wsf, unsigned short* __restrict__ wsh) {
  __shared__ float T[64][65];
  int bid = blockIdx.x, t = threadIdx.x;
  if (bid < 1024) {                  // 64x64 transpose tiles -> bf16 XT
    int nt = bid & 63, ct = (bid >> 6) & 3, b = bid >> 8;
    int c0 = ct * 64, n0 = nt * 64;
    int r = t >> 2, j = t & 3;
    const float* xr = x + ((size_t)b * CC + c0 + r) * NSP + n0 + j * 16;
    float4 f0 = *(const float4*)(xr);
    float4 f1 = *(const float4*)(xr + 4);
    float4 f2 = *(const float4*)(xr + 8);
    float4 f3 = *(const float4*)(xr + 12);
    *(float4*)&T[r][j * 16 + 0]  = f0;
    *(float4*)&T[r][j * 16 + 4]  = f1;
    *(float4*)&T[r][j * 16 + 8]  = f2;
    *(float4*)&T[r][j * 16 + 12] = f3;
    __syncthreads();
    int nr = t >> 2, j2 = t & 3;
    unsigned short o[16];
#pragma unroll
    for (int i = 0; i < 16; ++i) o[i] = f2bf(T[j2 * 16 + i][nr]);
    size_t to = ((size_t)b * NSP + n0 + nr) * CC + c0 + j2 * 16;
    *(uint4*)(wsh + H_XT + to)     = pack8(o);
    *(uint4*)(wsh + H_XT + to + 8) = pack8(o + 8);
  } else if (bid < 1028) {           // Wst bf16 stack: [g_w; theta_w; phi_w]
    int r0 = (bid - 1024) * 96;
    for (int i = 0; i < 96; ++i) {
      int rr = r0 + i;
      const float* src = (rr < 128) ? (g_w + (size_t)rr * CC)
                       : (rr < 256) ? (theta_w + (size_t)(rr - 128) * CC)
                                    : (phi_w + (size_t)(rr - 256) * CC);
      wsh[H_WST + (size_t)rr * CC + t] = f2bf(src[t]);
    }
  } else {                           // out_w bf16 + bias stack fp32
    for (int i = t; i < 32768; i += 256) wsh[H_OWH + i] = f2bf(out_w[i]);
    if (t < 128) {
      wsf[F_BST + t]       = g_b[t];
      wsf[F_BST + 128 + t] = theta_b[t];
      wsf[F_BST + 256 + t] = phi_b[t];
    }
  }
}

// ---- kB: projections Y[384x4096] = Wst @ XT^T + bias; store PG / TT ----
__global__ __launch_bounds__(256) void kB(const float* __restrict__ wsf,
                                          unsigned short* __restrict__ wsh) {
  __shared__ float bL[128];
  int bid = blockIdx.x;
  int b = bid / 96, rem = bid % 96;
  int r = rem >> 5, c = rem & 31;    // r: 0=g, 1=theta, 2=phi ; c: 128-col group
  int t = threadIdx.x, w = t >> 6, lane = t & 63;
  int wm = w >> 1, wn = w & 1;
  int lm = lane & 15, lq = lane >> 4;
  if (t < 128) bL[t] = wsf[F_BST + r * 128 + t];
  __syncthreads();

  const unsigned short* A = wsh + H_WST + (size_t)(r * 128 + wm * 64) * CC;
  const unsigned short* B = wsh + H_XT + ((size_t)b * NSP + c * 128 + wn * 64) * CC;
  f32x4 acc[4][4] = {};
  wave_gemm_bt(A, CC, B, CC, 256, lane, acc);

  int colb = c * 128 + wn * 64;
  if (r == 1) {                      // theta: store transposed TT[n][p]
    size_t tb = (size_t)b * 524288;
#pragma unroll
    for (int mi = 0; mi < 4; ++mi) {
      int p0 = wm * 64 + mi * 16 + lq * 4;
#pragma unroll
      for (int ni = 0; ni < 4; ++ni) {
        int col = colb + ni * 16 + lm;
        unsigned short u0 = f2bf(acc[mi][ni][0] + bL[p0 + 0]);
        unsigned short u1 = f2bf(acc[mi][ni][1] + bL[p0 + 1]);
        unsigned short u2 = f2bf(acc[mi][ni][2] + bL[p0 + 2]);
        unsigned short u3 = f2bf(acc[mi][ni][3] + bL[p0 + 3]);
        uint2 o;
        o.x = (unsigned)u0 | ((unsigned)u1 << 16);
        o.y = (unsigned)u2 | ((unsigned)u3 << 16);
        *(uint2*)(wsh + H_TT + tb + (size_t)col * 128 + p0) = o;
      }
    }
  } else {                           // g / phi: store row-major into PG
    int rbase = (r == 0) ? 0 : 128;
    size_t pbo = (size_t)b * 1048576;
#pragma unroll
    for (int mi = 0; mi < 4; ++mi)
#pragma unroll
      for (int rr = 0; rr < 4; ++rr) {
        int rl = wm * 64 + mi * 16 + lq * 4 + rr;
        float bv = bL[rl];
        size_t rowo = pbo + (size_t)(rbase + rl) * NSP;
#pragma unroll
        for (int ni = 0; ni < 4; ++ni)
          wsh[H_PG + rowo + colb + ni * 16 + lm] = f2bf(acc[mi][ni][rr] + bv);
      }
  }
}

// ---- kC: S'' = P~ @ G~^T (K=4096) -> LDS bf16; W2 = out_w @ S''(_bt) / N ----
__global__ __launch_bounds__(256) void kC(unsigned short* __restrict__ wsh) {
  __shared__ unsigned short Sh[128][136];   // padded pitch: 2-way banks on b128 reads
  int b = blockIdx.x;
  int t = threadIdx.x, w = t >> 6, lane = t & 63;
  int lm = lane & 15, lq = lane >> 4;
  int qm = w >> 1, qn = w & 1;

  {
    const unsigned short* A = wsh + H_PG + (size_t)b * 1048576 + (size_t)(128 + qm * 64) * NSP;
    const unsigned short* B = wsh + H_PG + (size_t)b * 1048576 + (size_t)(qn * 64) * NSP;
    f32x4 acc[4][4] = {};
    wave_gemm_bt2(A, NSP, B, NSP, NSP, lane, acc);
#pragma unroll
    for (int mi = 0; mi < 4; ++mi)
#pragma unroll
      for (int rr = 0; rr < 4; ++rr) {
        int p = qm * 64 + mi * 16 + lq * 4 + rr;
#pragma unroll
        for (int ni = 0; ni < 4; ++ni)
          Sh[p][qn * 64 + ni * 16 + lm] = f2bf(acc[mi][ni][rr]);
      }
  }
  __syncthreads();

  // W2[i][p] = sum_g out_w[i][g] * S''[p][g] / N
  {
    const unsigned short* A2 = wsh + H_OWH + (size_t)(w * 64) * 128;
    f32x4 acc2[4][8] = {};
    for (int k = 0; k < 128; k += 32) {
      bf16x8 a[4], bb[8];
#pragma unroll
      for (int i = 0; i < 4; ++i)
        a[i] = *(const bf16x8*)(A2 + (size_t)(i * 16 + lm) * 128 + lq * 8 + k);
#pragma unroll
      for (int j = 0; j < 8; ++j)
        bb[j] = *(const bf16x8*)(&Sh[j * 16 + lm][lq * 8 + k]);
#pragma unroll
      for (int mi = 0; mi < 4; ++mi)
#pragma unroll
        for (int nj = 0; nj < 8; ++nj)
          acc2[mi][nj] = __builtin_amdgcn_mfma_f32_16x16x32_bf16(a[mi], bb[nj], acc2[mi][nj], 0, 0, 0);
    }
    const float inv = 1.0f / 4096.0f;
#pragma unroll
    for (int mi = 0; mi < 4; ++mi)
#pragma unroll
      for (int rr = 0; rr < 4; ++rr) {
        int i = w * 64 + mi * 16 + lq * 4 + rr;
        size_t rowo = (size_t)b * 32768 + (size_t)i * 128;
#pragma unroll
        for (int nj = 0; nj < 8; ++nj)
          wsh[H_W2 + rowo + nj * 16 + lm] = f2bf(acc2[mi][nj][rr] * inv);
      }
  }
}

// ---- kD: out = x + W2 @ TT(_bt) + out_b ----
__global__ __launch_bounds__(256) void kD(const unsigned short* __restrict__ wsh,
                                          const float* __restrict__ x,
                                          const float* __restrict__ out_b,
                                          float* __restrict__ out) {
  int bid = blockIdx.x;
  int b = bid >> 6, r6 = bid & 63;
  int tm = r6 >> 5, tn = r6 & 31;
  int t = threadIdx.x, w = t >> 6, lane = t & 63;
  int wm = w >> 1, wn = w & 1;
  int rb = tm * 128 + wm * 64, cb = tn * 128 + wn * 64;
  const unsigned short* A = wsh + H_W2 + (size_t)b * 32768 + (size_t)rb * 128;
  const unsigned short* B = wsh + H_TT + (size_t)b * 524288 + (size_t)cb * 128;
  f32x4 acc[4][4] = {};
  wave_gemm_bt(A, 128, B, 128, 128, lane, acc);
  int lm = lane & 15, lq = lane >> 4;
#pragma unroll
  for (int mi = 0; mi < 4; ++mi)
#pragma unroll
    for (int rr = 0; rr < 4; ++rr) {
      int row = rb + mi * 16 + lq * 4 + rr;
      float bi = out_b[row];
#pragma unroll
      for (int ni = 0; ni < 4; ++ni) {
        int col = cb + ni * 16 + lm;
        size_t off = ((size_t)b * CC + row) * NSP + col;
        out[off] = acc[mi][ni][rr] + x[off] + bi;
      }
    }
}

extern "C" void kernel_launch(void* const* d_in, const int* in_sizes, int n_in,
                              void* d_out, int out_size, void* d_ws, size_t ws_size,
                              hipStream_t stream) {
  const float* x       = (const float*)d_in[0];
  const float* g_w     = (const float*)d_in[1];
  const float* g_b     = (const float*)d_in[2];
  const float* theta_w = (const float*)d_in[3];
  const float* theta_b = (const float*)d_in[4];
  const float* phi_w   = (const float*)d_in[5];
  const float* phi_b   = (const float*)d_in[6];
  const float* out_w   = (const float*)d_in[7];
  const float* out_b   = (const float*)d_in[8];
  float* wsf = (float*)d_ws;
  unsigned short* wsh = (unsigned short*)(wsf + 512);
  float* out = (float*)d_out;

  kA<<<dim3(1029), dim3(256), 0, stream>>>(g_w, theta_w, phi_w, out_w,
                                           g_b, theta_b, phi_b, x, wsf, wsh);
  kB<<<dim3(384), dim3(256), 0, stream>>>(wsf, wsh);
  kC<<<dim3(4), dim3(256), 0, stream>>>(wsh);
  kD<<<dim3(256), dim3(256), 0, stream>>>(wsh, x, out_b, out);
}

// Round 2
// 155.656 us; speedup vs baseline: 1.5927x; 1.5927x over previous
//
#include <hip/hip_runtime.h>
#include <hip/hip_bf16.h>

// Non-local block via rank-128 factorization (no 256x256 Gram):
//   G~ = g_w x + g_b ; T~ = theta_w x + theta_b ; P~ = phi_w x + phi_b   [128x4096]/batch
//   S''[p][g] = sum_n P~[p][n] G~[g][n]                                  [128x128]/batch
//   W2 = out_w @ S''^T / N                                               [256x128]/batch
//   out = x + W2 @ T~ + out_b
// 5 launches:
//  kA:  x -> bf16 XT [n][c] transpose (LDS) + weight stack bf16 + out_w bf16 + biases
//  kB:  projections [384x4096] = Wst @ XT^T(+bias); P,G -> PG rows; T -> TT transposed
//  kC1: split-K S'' partials (4 batches x 16 chunks of K=256, grid 64, fp32 partials)
//  kC2: reduce partials (fp32) -> S'' bf16 in LDS ; W2 = out_w @ S''(_bt) / N -> bf16
//  kD:  out = x + W2 @ TT(_bt) + out_b

#define CC   256
#define NSP  4096
#define NB   4
#define KSPLIT 16

typedef __attribute__((ext_vector_type(8))) short bf16x8;
typedef __attribute__((ext_vector_type(4))) float f32x4;

// fp32 region (float offsets from wsf)
#define F_BST  0                    // [384] biases (g,theta,phi)
#define F_PART 512                  // [4][16][128][128] fp32 S'' partials
#define F_WEND 1049088              // = 512 + 4*16*16384
// bf16 region (ushort offsets from wsh = wsf + F_WEND)
#define H_XT   0                    // [4][4096][256]
#define H_PG   4194304              // [4][256][4096]  rows 0-127 = G~, 128-255 = P~
#define H_TT   8388608              // [4][4096][128]  TT[n][p] = T~[p][n]
#define H_WST  10485760             // [384][256]  rows: g_w / theta_w / phi_w
#define H_OWH  10584064             // [256][128]  out_w bf16
#define H_W2   10616832             // [4][256][128]

__device__ __forceinline__ unsigned short f2bf(float f) {
  __hip_bfloat16 h = __float2bfloat16(f);
  return __builtin_bit_cast(unsigned short, h);
}
__device__ __forceinline__ uint4 pack8(const unsigned short* h) {
  uint4 u;
  u.x = (unsigned)h[0] | ((unsigned)h[1] << 16);
  u.y = (unsigned)h[2] | ((unsigned)h[3] << 16);
  u.z = (unsigned)h[4] | ((unsigned)h[5] << 16);
  u.w = (unsigned)h[6] | ((unsigned)h[7] << 16);
  return u;
}

// Wave computes C[64x64] += A[64xK] * B^T[64xK] (bf16 row-major, K contiguous), 1-deep prefetch.
__device__ __forceinline__ void wave_gemm_bt(const unsigned short* __restrict__ A, int pitchA,
                                             const unsigned short* __restrict__ B, int pitchB,
                                             int K, int lane, f32x4 acc[4][4]) {
  int lm = lane & 15, lq = lane >> 4;
  const unsigned short* ap[4];
  const unsigned short* bp[4];
#pragma unroll
  for (int i = 0; i < 4; ++i) {
    ap[i] = A + (size_t)(i * 16 + lm) * pitchA + lq * 8;
    bp[i] = B + (size_t)(i * 16 + lm) * pitchB + lq * 8;
  }
  bf16x8 a0[4], b0[4];
#pragma unroll
  for (int i = 0; i < 4; ++i) {
    a0[i] = *(const bf16x8*)(ap[i]);
    b0[i] = *(const bf16x8*)(bp[i]);
  }
  for (int k = 32; k < K; k += 32) {
    bf16x8 a1[4], b1[4];
#pragma unroll
    for (int i = 0; i < 4; ++i) {
      a1[i] = *(const bf16x8*)(ap[i] + k);
      b1[i] = *(const bf16x8*)(bp[i] + k);
    }
#pragma unroll
    for (int mi = 0; mi < 4; ++mi)
#pragma unroll
      for (int ni = 0; ni < 4; ++ni)
        acc[mi][ni] = __builtin_amdgcn_mfma_f32_16x16x32_bf16(a0[mi], b0[ni], acc[mi][ni], 0, 0, 0);
#pragma unroll
    for (int i = 0; i < 4; ++i) { a0[i] = a1[i]; b0[i] = b1[i]; }
  }
#pragma unroll
  for (int mi = 0; mi < 4; ++mi)
#pragma unroll
    for (int ni = 0; ni < 4; ++ni)
      acc[mi][ni] = __builtin_amdgcn_mfma_f32_16x16x32_bf16(a0[mi], b0[ni], acc[mi][ni], 0, 0, 0);
}

// ---- kA: XT transpose (x fp32 -> bf16 [n][c]) + weight stack + out_w bf16 + biases ----
__global__ __launch_bounds__(256) void kA(
    const float* __restrict__ g_w, const float* __restrict__ theta_w,
    const float* __restrict__ phi_w, const float* __restrict__ out_w,
    const float* __restrict__ g_b, const float* __restrict__ theta_b,
    const float* __restrict__ phi_b, const float* __restrict__ x,
    float* __restrict__ wsf, unsigned short* __restrict__ wsh) {
  __shared__ float T[64][65];
  int bid = blockIdx.x, t = threadIdx.x;
  if (bid < 1024) {                  // 64x64 transpose tiles -> bf16 XT
    int nt = bid & 63, ct = (bid >> 6) & 3, b = bid >> 8;
    int c0 = ct * 64, n0 = nt * 64;
    int r = t >> 2, j = t & 3;
    const float* xr = x + ((size_t)b * CC + c0 + r) * NSP + n0 + j * 16;
    float4 f0 = *(const float4*)(xr);
    float4 f1 = *(const float4*)(xr + 4);
    float4 f2 = *(const float4*)(xr + 8);
    float4 f3 = *(const float4*)(xr + 12);
    *(float4*)&T[r][j * 16 + 0]  = f0;
    *(float4*)&T[r][j * 16 + 4]  = f1;
    *(float4*)&T[r][j * 16 + 8]  = f2;
    *(float4*)&T[r][j * 16 + 12] = f3;
    __syncthreads();
    int nr = t >> 2, j2 = t & 3;
    unsigned short o[16];
#pragma unroll
    for (int i = 0; i < 16; ++i) o[i] = f2bf(T[j2 * 16 + i][nr]);
    size_t to = ((size_t)b * NSP + n0 + nr) * CC + c0 + j2 * 16;
    *(uint4*)(wsh + H_XT + to)     = pack8(o);
    *(uint4*)(wsh + H_XT + to + 8) = pack8(o + 8);
  } else if (bid < 1028) {           // Wst bf16 stack: [g_w; theta_w; phi_w]
    int r0 = (bid - 1024) * 96;
    for (int i = 0; i < 96; ++i) {
      int rr = r0 + i;
      const float* src = (rr < 128) ? (g_w + (size_t)rr * CC)
                       : (rr < 256) ? (theta_w + (size_t)(rr - 128) * CC)
                                    : (phi_w + (size_t)(rr - 256) * CC);
      wsh[H_WST + (size_t)rr * CC + t] = f2bf(src[t]);
    }
  } else {                           // out_w bf16 + bias stack fp32
    for (int i = t; i < 32768; i += 256) wsh[H_OWH + i] = f2bf(out_w[i]);
    if (t < 128) {
      wsf[F_BST + t]       = g_b[t];
      wsf[F_BST + 128 + t] = theta_b[t];
      wsf[F_BST + 256 + t] = phi_b[t];
    }
  }
}

// ---- kB: projections Y[384x4096] = Wst @ XT^T + bias; store PG / TT ----
__global__ __launch_bounds__(256) void kB(const float* __restrict__ wsf,
                                          unsigned short* __restrict__ wsh) {
  __shared__ float bL[128];
  int bid = blockIdx.x;
  int b = bid / 96, rem = bid % 96;
  int r = rem >> 5, c = rem & 31;    // r: 0=g, 1=theta, 2=phi ; c: 128-col group
  int t = threadIdx.x, w = t >> 6, lane = t & 63;
  int wm = w >> 1, wn = w & 1;
  int lm = lane & 15, lq = lane >> 4;
  if (t < 128) bL[t] = wsf[F_BST + r * 128 + t];
  __syncthreads();

  const unsigned short* A = wsh + H_WST + (size_t)(r * 128 + wm * 64) * CC;
  const unsigned short* B = wsh + H_XT + ((size_t)b * NSP + c * 128 + wn * 64) * CC;
  f32x4 acc[4][4] = {};
  wave_gemm_bt(A, CC, B, CC, 256, lane, acc);

  int colb = c * 128 + wn * 64;
  if (r == 1) {                      // theta: store transposed TT[n][p]
    size_t tb = (size_t)b * 524288;
#pragma unroll
    for (int mi = 0; mi < 4; ++mi) {
      int p0 = wm * 64 + mi * 16 + lq * 4;
#pragma unroll
      for (int ni = 0; ni < 4; ++ni) {
        int col = colb + ni * 16 + lm;
        unsigned short u0 = f2bf(acc[mi][ni][0] + bL[p0 + 0]);
        unsigned short u1 = f2bf(acc[mi][ni][1] + bL[p0 + 1]);
        unsigned short u2 = f2bf(acc[mi][ni][2] + bL[p0 + 2]);
        unsigned short u3 = f2bf(acc[mi][ni][3] + bL[p0 + 3]);
        uint2 o;
        o.x = (unsigned)u0 | ((unsigned)u1 << 16);
        o.y = (unsigned)u2 | ((unsigned)u3 << 16);
        *(uint2*)(wsh + H_TT + tb + (size_t)col * 128 + p0) = o;
      }
    }
  } else {                           // g / phi: store row-major into PG
    int rbase = (r == 0) ? 0 : 128;
    size_t pbo = (size_t)b * 1048576;
#pragma unroll
    for (int mi = 0; mi < 4; ++mi)
#pragma unroll
      for (int rr = 0; rr < 4; ++rr) {
        int rl = wm * 64 + mi * 16 + lq * 4 + rr;
        float bv = bL[rl];
        size_t rowo = pbo + (size_t)(rbase + rl) * NSP;
#pragma unroll
        for (int ni = 0; ni < 4; ++ni)
          wsh[H_PG + rowo + colb + ni * 16 + lm] = f2bf(acc[mi][ni][rr] + bv);
      }
  }
}

// ---- kC1: split-K S'' partials. grid = 4 batches x 16 chunks (K=256 each) ----
__global__ __launch_bounds__(256) void kC1(const unsigned short* __restrict__ wsh,
                                           float* __restrict__ wsf) {
  int bid = blockIdx.x;
  int b = bid >> 4, ks = bid & 15;
  int t = threadIdx.x, w = t >> 6, lane = t & 63;
  int lm = lane & 15, lq = lane >> 4;
  int qm = w >> 1, qn = w & 1;
  const unsigned short* A = wsh + H_PG + (size_t)b * 1048576 +
                            (size_t)(128 + qm * 64) * NSP + ks * 256;
  const unsigned short* B = wsh + H_PG + (size_t)b * 1048576 +
                            (size_t)(qn * 64) * NSP + ks * 256;
  f32x4 acc[4][4] = {};
  wave_gemm_bt(A, NSP, B, NSP, 256, lane, acc);
  float* P = wsf + F_PART + (size_t)(b * KSPLIT + ks) * 16384;
#pragma unroll
  for (int mi = 0; mi < 4; ++mi)
#pragma unroll
    for (int rr = 0; rr < 4; ++rr) {
      int p = qm * 64 + mi * 16 + lq * 4 + rr;
#pragma unroll
      for (int ni = 0; ni < 4; ++ni)
        P[p * 128 + qn * 64 + ni * 16 + lm] = acc[mi][ni][rr];
    }
}

// ---- kC2: reduce partials -> S'' bf16 in LDS ; W2 = out_w @ S''(_bt) / N ----
__global__ __launch_bounds__(256) void kC2(const float* __restrict__ wsf,
                                           unsigned short* __restrict__ wsh) {
  __shared__ unsigned short Sh[128][136];
  int b = blockIdx.x;
  int t = threadIdx.x, w = t >> 6, lane = t & 63;
  int lm = lane & 15, lq = lane >> 4;

  // reduce 16 fp32 partials -> bf16 S'' (coalesced float4 per thread)
  const float* PB = wsf + F_PART + (size_t)b * KSPLIT * 16384;
#pragma unroll
  for (int e = 0; e < 16; ++e) {
    int base = (e * 256 + t) * 4;
    float4 s = {0.f, 0.f, 0.f, 0.f};
#pragma unroll
    for (int ks = 0; ks < KSPLIT; ++ks) {
      float4 p = *(const float4*)(PB + (size_t)ks * 16384 + base);
      s.x += p.x; s.y += p.y; s.z += p.z; s.w += p.w;
    }
    int pr = base >> 7, g = base & 127;
    uint2 o;
    o.x = (unsigned)f2bf(s.x) | ((unsigned)f2bf(s.y) << 16);
    o.y = (unsigned)f2bf(s.z) | ((unsigned)f2bf(s.w) << 16);
    *(uint2*)(&Sh[pr][g]) = o;
  }
  __syncthreads();

  // W2[i][p] = sum_g out_w[i][g] * S''[p][g] / N
  const unsigned short* A2 = wsh + H_OWH + (size_t)(w * 64) * 128;
  f32x4 acc2[4][8] = {};
  for (int k = 0; k < 128; k += 32) {
    bf16x8 a[4], bb[8];
#pragma unroll
    for (int i = 0; i < 4; ++i)
      a[i] = *(const bf16x8*)(A2 + (size_t)(i * 16 + lm) * 128 + lq * 8 + k);
#pragma unroll
    for (int j = 0; j < 8; ++j)
      bb[j] = *(const bf16x8*)(&Sh[j * 16 + lm][lq * 8 + k]);
#pragma unroll
    for (int mi = 0; mi < 4; ++mi)
#pragma unroll
      for (int nj = 0; nj < 8; ++nj)
        acc2[mi][nj] = __builtin_amdgcn_mfma_f32_16x16x32_bf16(a[mi], bb[nj], acc2[mi][nj], 0, 0, 0);
  }
  const float inv = 1.0f / 4096.0f;
#pragma unroll
  for (int mi = 0; mi < 4; ++mi)
#pragma unroll
    for (int rr = 0; rr < 4; ++rr) {
      int i = w * 64 + mi * 16 + lq * 4 + rr;
      size_t rowo = (size_t)b * 32768 + (size_t)i * 128;
#pragma unroll
      for (int nj = 0; nj < 8; ++nj)
        wsh[H_W2 + rowo + nj * 16 + lm] = f2bf(acc2[mi][nj][rr] * inv);
    }
}

// ---- kD: out = x + W2 @ TT(_bt) + out_b ----
__global__ __launch_bounds__(256) void kD(const unsigned short* __restrict__ wsh,
                                          const float* __restrict__ x,
                                          const float* __restrict__ out_b,
                                          float* __restrict__ out) {
  int bid = blockIdx.x;
  int b = bid >> 6, r6 = bid & 63;
  int tm = r6 >> 5, tn = r6 & 31;
  int t = threadIdx.x, w = t >> 6, lane = t & 63;
  int wm = w >> 1, wn = w & 1;
  int rb = tm * 128 + wm * 64, cb = tn * 128 + wn * 64;
  const unsigned short* A = wsh + H_W2 + (size_t)b * 32768 + (size_t)rb * 128;
  const unsigned short* B = wsh + H_TT + (size_t)b * 524288 + (size_t)cb * 128;
  f32x4 acc[4][4] = {};
  wave_gemm_bt(A, 128, B, 128, 128, lane, acc);
  int lm = lane & 15, lq = lane >> 4;
#pragma unroll
  for (int mi = 0; mi < 4; ++mi)
#pragma unroll
    for (int rr = 0; rr < 4; ++rr) {
      int row = rb + mi * 16 + lq * 4 + rr;
      float bi = out_b[row];
#pragma unroll
      for (int ni = 0; ni < 4; ++ni) {
        int col = cb + ni * 16 + lm;
        size_t off = ((size_t)b * CC + row) * NSP + col;
        out[off] = acc[mi][ni][rr] + x[off] + bi;
      }
    }
}

extern "C" void kernel_launch(void* const* d_in, const int* in_sizes, int n_in,
                              void* d_out, int out_size, void* d_ws, size_t ws_size,
                              hipStream_t stream) {
  const float* x       = (const float*)d_in[0];
  const float* g_w     = (const float*)d_in[1];
  const float* g_b     = (const float*)d_in[2];
  const float* theta_w = (const float*)d_in[3];
  const float* theta_b = (const float*)d_in[4];
  const float* phi_w   = (const float*)d_in[5];
  const float* phi_b   = (const float*)d_in[6];
  const float* out_w   = (const float*)d_in[7];
  const float* out_b   = (const float*)d_in[8];
  float* wsf = (float*)d_ws;
  unsigned short* wsh = (unsigned short*)(wsf + F_WEND);
  float* out = (float*)d_out;

  kA<<<dim3(1029), dim3(256), 0, stream>>>(g_w, theta_w, phi_w, out_w,
                                           g_b, theta_b, phi_b, x, wsf, wsh);
  kB<<<dim3(384), dim3(256), 0, stream>>>(wsf, wsh);
  kC1<<<dim3(64), dim3(256), 0, stream>>>(wsh, wsf);
  kC2<<<dim3(4), dim3(256), 0, stream>>>(wsf, wsh);
  kD<<<dim3(256), dim3(256), 0, stream>>>(wsh, x, out_b, out);
}

// Round 3
// 138.565 us; speedup vs baseline: 1.7892x; 1.1233x over previous
//
#include <hip/hip_runtime.h>
#include <hip/hip_bf16.h>

// Non-local block via rank-128 factorization:
//   G~ = g_w x + g_b ; T~ = theta_w x + theta_b ; P~ = phi_w x + phi_b   [128x4096]/batch
//   S''[p][g] = sum_n P~[p][n] G~[g][n]                                  [128x128]/batch
//   W2 = out_w @ S''^T / N                                               [256x128]/batch
//   out = x + W2 @ T~ + out_b
// 4 launches:
//  kP: fused transpose-in-LDS + projections; weights cvt in-reg; -> PG rows / TT transposed
//  kS: split-K S'' partials (4 batches x 16 chunks of K=256, grid 64, fp32 partials)
//  kR: reduce partials (grid 64, coalesced) -> S'' bf16
//  kD: per-block W2 = out_w @ S''(_bt)/N into LDS (redundant, tiny) + out = x + W2@TT + out_b

#define CC   256
#define NSP  4096
#define NB   4
#define KSPLIT 16

typedef __attribute__((ext_vector_type(8))) short bf16x8;
typedef __attribute__((ext_vector_type(4))) float f32x4;

// fp32 region (float offsets from wsf): [4][16][128][128] S'' partials
#define F_WEND 1048576
// bf16 region (ushort offsets from wsh = wsf + F_WEND)
#define H_PG   0                    // [4][256][4096]  rows 0-127 = G~, 128-255 = P~
#define H_TT   4194304              // [4][4096][128]  TT[n][p] = T~[p][n]
#define H_S2   6291456              // [4][128][128]   S'' bf16

__device__ __forceinline__ unsigned short f2bf(float f) {
  __hip_bfloat16 h = __float2bfloat16(f);
  return __builtin_bit_cast(unsigned short, h);
}
__device__ __forceinline__ uint4 pack8(const unsigned short* h) {
  uint4 u;
  u.x = (unsigned)h[0] | ((unsigned)h[1] << 16);
  u.y = (unsigned)h[2] | ((unsigned)h[3] << 16);
  u.z = (unsigned)h[4] | ((unsigned)h[5] << 16);
  u.w = (unsigned)h[6] | ((unsigned)h[7] << 16);
  return u;
}
// load 8 consecutive fp32, convert RNE -> bf16x8
__device__ __forceinline__ bf16x8 ld_cvt8(const float* __restrict__ p) {
  float4 lo = *(const float4*)p;
  float4 hi = *(const float4*)(p + 4);
  bf16x8 r;
  r[0] = (short)f2bf(lo.x); r[1] = (short)f2bf(lo.y);
  r[2] = (short)f2bf(lo.z); r[3] = (short)f2bf(lo.w);
  r[4] = (short)f2bf(hi.x); r[5] = (short)f2bf(hi.y);
  r[6] = (short)f2bf(hi.z); r[7] = (short)f2bf(hi.w);
  return r;
}

// Wave computes C[64x64] += A[64xK] * B^T[64xK] (bf16 row-major, K contiguous), 1-deep prefetch.
__device__ __forceinline__ void wave_gemm_bt(const unsigned short* __restrict__ A, int pitchA,
                                             const unsigned short* __restrict__ B, int pitchB,
                                             int K, int lane, f32x4 acc[4][4]) {
  int lm = lane & 15, lq = lane >> 4;
  const unsigned short* ap[4];
  const unsigned short* bp[4];
#pragma unroll
  for (int i = 0; i < 4; ++i) {
    ap[i] = A + (size_t)(i * 16 + lm) * pitchA + lq * 8;
    bp[i] = B + (size_t)(i * 16 + lm) * pitchB + lq * 8;
  }
  bf16x8 a0[4], b0[4];
#pragma unroll
  for (int i = 0; i < 4; ++i) {
    a0[i] = *(const bf16x8*)(ap[i]);
    b0[i] = *(const bf16x8*)(bp[i]);
  }
  for (int k = 32; k < K; k += 32) {
    bf16x8 a1[4], b1[4];
#pragma unroll
    for (int i = 0; i < 4; ++i) {
      a1[i] = *(const bf16x8*)(ap[i] + k);
      b1[i] = *(const bf16x8*)(bp[i] + k);
    }
#pragma unroll
    for (int mi = 0; mi < 4; ++mi)
#pragma unroll
      for (int ni = 0; ni < 4; ++ni)
        acc[mi][ni] = __builtin_amdgcn_mfma_f32_16x16x32_bf16(a0[mi], b0[ni], acc[mi][ni], 0, 0, 0);
#pragma unroll
    for (int i = 0; i < 4; ++i) { a0[i] = a1[i]; b0[i] = b1[i]; }
  }
#pragma unroll
  for (int mi = 0; mi < 4; ++mi)
#pragma unroll
    for (int ni = 0; ni < 4; ++ni)
      acc[mi][ni] = __builtin_amdgcn_mfma_f32_16x16x32_bf16(a0[mi], b0[ni], acc[mi][ni], 0, 0, 0);
}

// ---- kP: fused X-transpose (LDS) + projections ----
// grid 128 = 4 batches x 32 col-slices(128). Per block:
//   stage X[256k x 128n] -> XL[n][k] bf16 (XOR-swizzled) via fp32 LDS tile T
//   3 rounds r (g/theta/phi): Y[128 x 128] = W_r @ X(+b_r); W_r cvt fp32->bf16 in-reg
//   r==1 -> TT transposed ; r==0/2 -> PG rows
__global__ __launch_bounds__(256) void kP(
    const float* __restrict__ g_w, const float* __restrict__ theta_w,
    const float* __restrict__ phi_w, const float* __restrict__ g_b,
    const float* __restrict__ theta_b, const float* __restrict__ phi_b,
    const float* __restrict__ x, unsigned short* __restrict__ wsh) {
  __shared__ float T[64][65];
  __shared__ unsigned short XL[128 * 256];   // [n][k], byte ^= ((n&7)<<4)
  __shared__ float biasL[384];
  int bid = blockIdx.x;
  int b = bid >> 5, c = bid & 31;
  int t = threadIdx.x;
  if (t < 128) {
    biasL[t]       = g_b[t];
    biasL[128 + t] = theta_b[t];
    biasL[256 + t] = phi_b[t];
  }
  // ---- stage: 8 sub-tiles of 64x64 ----
  for (int s = 0; s < 8; ++s) {
    int kb = s >> 1, nb = s & 1;
    int r = t >> 2, j = t & 3;
    const float* xr = x + ((size_t)b * CC + kb * 64 + r) * NSP + c * 128 + nb * 64 + j * 16;
    float4 f0 = *(const float4*)(xr);
    float4 f1 = *(const float4*)(xr + 4);
    float4 f2 = *(const float4*)(xr + 8);
    float4 f3 = *(const float4*)(xr + 12);
    *(float4*)&T[r][j * 16 + 0]  = f0;
    *(float4*)&T[r][j * 16 + 4]  = f1;
    *(float4*)&T[r][j * 16 + 8]  = f2;
    *(float4*)&T[r][j * 16 + 12] = f3;
    __syncthreads();
    int nr = t >> 2, j2 = t & 3;
    unsigned short o[16];
#pragma unroll
    for (int i = 0; i < 16; ++i) o[i] = f2bf(T[j2 * 16 + i][nr]);
    int row = nb * 64 + nr;
    int kidx = kb * 64 + j2 * 16;
    int sw = (row & 7) << 3;                 // ushort-index XOR (== byte<<4)
    *(uint4*)(XL + ((row * 256 + kidx) ^ sw))     = pack8(o);
    *(uint4*)(XL + ((row * 256 + kidx + 8) ^ sw)) = pack8(o + 8);
    __syncthreads();
  }

  // ---- projections ----
  int w = t >> 6, lane = t & 63;
  int wm = w >> 1, wn = w & 1;
  int lm = lane & 15, lq = lane >> 4;
  int bsw = (lm & 7) << 3;
#pragma unroll
  for (int r = 0; r < 3; ++r) {
    const float* wptr = (r == 0) ? g_w : (r == 1) ? theta_w : phi_w;
    const float* ap[4];
    int bidx[4];
#pragma unroll
    for (int i = 0; i < 4; ++i) {
      ap[i] = wptr + (size_t)(wm * 64 + i * 16 + lm) * CC + lq * 8;
      bidx[i] = (wn * 64 + i * 16 + lm) * 256 + lq * 8;
    }
    f32x4 acc[4][4] = {};
    bf16x8 a0[4], b0[4];
#pragma unroll
    for (int i = 0; i < 4; ++i) {
      a0[i] = ld_cvt8(ap[i]);
      b0[i] = *(const bf16x8*)(XL + (bidx[i] ^ bsw));
    }
    for (int k = 32; k < 256; k += 32) {
      bf16x8 a1[4], b1[4];
#pragma unroll
      for (int i = 0; i < 4; ++i) {
        a1[i] = ld_cvt8(ap[i] + k);
        b1[i] = *(const bf16x8*)(XL + ((bidx[i] + k) ^ bsw));
      }
#pragma unroll
      for (int mi = 0; mi < 4; ++mi)
#pragma unroll
        for (int ni = 0; ni < 4; ++ni)
          acc[mi][ni] = __builtin_amdgcn_mfma_f32_16x16x32_bf16(a0[mi], b0[ni], acc[mi][ni], 0, 0, 0);
#pragma unroll
      for (int i = 0; i < 4; ++i) { a0[i] = a1[i]; b0[i] = b1[i]; }
    }
#pragma unroll
    for (int mi = 0; mi < 4; ++mi)
#pragma unroll
      for (int ni = 0; ni < 4; ++ni)
        acc[mi][ni] = __builtin_amdgcn_mfma_f32_16x16x32_bf16(a0[mi], b0[ni], acc[mi][ni], 0, 0, 0);

    if (r == 1) {                    // theta: store transposed TT[n][p]
      size_t tb = (size_t)b * 524288;
#pragma unroll
      for (int mi = 0; mi < 4; ++mi) {
        int p0 = wm * 64 + mi * 16 + lq * 4;
#pragma unroll
        for (int ni = 0; ni < 4; ++ni) {
          int n = c * 128 + wn * 64 + ni * 16 + lm;
          unsigned short u0 = f2bf(acc[mi][ni][0] + biasL[128 + p0 + 0]);
          unsigned short u1 = f2bf(acc[mi][ni][1] + biasL[128 + p0 + 1]);
          unsigned short u2 = f2bf(acc[mi][ni][2] + biasL[128 + p0 + 2]);
          unsigned short u3 = f2bf(acc[mi][ni][3] + biasL[128 + p0 + 3]);
          uint2 o;
          o.x = (unsigned)u0 | ((unsigned)u1 << 16);
          o.y = (unsigned)u2 | ((unsigned)u3 << 16);
          *(uint2*)(wsh + H_TT + tb + (size_t)n * 128 + p0) = o;
        }
      }
    } else {                         // g/phi: PG rows
      int rbase = (r == 0) ? 0 : 128;
      size_t pbo = (size_t)b * 1048576;
#pragma unroll
      for (int mi = 0; mi < 4; ++mi)
#pragma unroll
        for (int rr = 0; rr < 4; ++rr) {
          int rl = wm * 64 + mi * 16 + lq * 4 + rr;
          float bv = biasL[r * 128 + rl];
          size_t rowo = pbo + (size_t)(rbase + rl) * NSP;
#pragma unroll
          for (int ni = 0; ni < 4; ++ni)
            wsh[H_PG + rowo + c * 128 + wn * 64 + ni * 16 + lm] = f2bf(acc[mi][ni][rr] + bv);
        }
    }
  }
}

// ---- kS: split-K S'' partials. grid = 4 batches x 16 chunks (K=256 each) ----
__global__ __launch_bounds__(256) void kS(const unsigned short* __restrict__ wsh,
                                          float* __restrict__ wsf) {
  int bid = blockIdx.x;
  int b = bid >> 4, ks = bid & 15;
  int t = threadIdx.x, w = t >> 6, lane = t & 63;
  int lm = lane & 15, lq = lane >> 4;
  int qm = w >> 1, qn = w & 1;
  const unsigned short* A = wsh + H_PG + (size_t)b * 1048576 +
                            (size_t)(128 + qm * 64) * NSP + ks * 256;
  const unsigned short* B = wsh + H_PG + (size_t)b * 1048576 +
                            (size_t)(qn * 64) * NSP + ks * 256;
  f32x4 acc[4][4] = {};
  wave_gemm_bt(A, NSP, B, NSP, 256, lane, acc);
  float* P = wsf + (size_t)(b * KSPLIT + ks) * 16384;
#pragma unroll
  for (int mi = 0; mi < 4; ++mi)
#pragma unroll
    for (int rr = 0; rr < 4; ++rr) {
      int p = qm * 64 + mi * 16 + lq * 4 + rr;
#pragma unroll
      for (int ni = 0; ni < 4; ++ni)
        P[p * 128 + qn * 64 + ni * 16 + lm] = acc[mi][ni][rr];
    }
}

// ---- kR: reduce partials -> S'' bf16. grid 64 = 4 batches x 16 slices ----
__global__ __launch_bounds__(256) void kR(const float* __restrict__ wsf,
                                          unsigned short* __restrict__ wsh) {
  int bid = blockIdx.x;
  int b = bid >> 4, e = bid & 15;
  int t = threadIdx.x;
  int base = e * 1024 + t * 4;
  const float* PB = wsf + (size_t)b * KSPLIT * 16384;
  float4 s = {0.f, 0.f, 0.f, 0.f};
#pragma unroll
  for (int ks = 0; ks < KSPLIT; ++ks) {
    float4 p = *(const float4*)(PB + (size_t)ks * 16384 + base);
    s.x += p.x; s.y += p.y; s.z += p.z; s.w += p.w;
  }
  uint2 o;
  o.x = (unsigned)f2bf(s.x) | ((unsigned)f2bf(s.y) << 16);
  o.y = (unsigned)f2bf(s.z) | ((unsigned)f2bf(s.w) << 16);
  *(uint2*)(wsh + H_S2 + (size_t)b * 16384 + base) = o;
}

// ---- kD: per-block W2 (K=128 mini-GEMM, into swizzled LDS) + out = x + W2@TT + out_b ----
__global__ __launch_bounds__(256) void kD(const unsigned short* __restrict__ wsh,
                                          const float* __restrict__ out_w,
                                          const float* __restrict__ x,
                                          const float* __restrict__ out_b,
                                          float* __restrict__ out) {
  __shared__ unsigned short W2L[128 * 128];  // [i_local][p], byte ^= ((i&7)<<4)
  int bid = blockIdx.x;
  int b = bid >> 6, r6 = bid & 63;
  int tm = r6 >> 5, tn = r6 & 31;
  int t = threadIdx.x, w = t >> 6, lane = t & 63;
  int lm = lane & 15, lq = lane >> 4;
  int rb = tm * 128;                 // global W2 row base for this block

  // mini-GEMM: W2^T tile per wave: A = S2 rows p, B = out_w rows i (cvt in-reg)
  {
    int pm = w >> 1, im = w & 1;
    const unsigned short* As = wsh + H_S2 + (size_t)b * 16384;
    f32x4 macc[4][4] = {};
    for (int kk = 0; kk < 128; kk += 32) {
      bf16x8 a[4], bb[4];
#pragma unroll
      for (int i = 0; i < 4; ++i) {
        a[i]  = *(const bf16x8*)(As + (size_t)(pm * 64 + i * 16 + lm) * 128 + lq * 8 + kk);
        bb[i] = ld_cvt8(out_w + (size_t)(rb + im * 64 + i * 16 + lm) * 128 + lq * 8 + kk);
      }
#pragma unroll
      for (int mi = 0; mi < 4; ++mi)
#pragma unroll
        for (int ni = 0; ni < 4; ++ni)
          macc[mi][ni] = __builtin_amdgcn_mfma_f32_16x16x32_bf16(a[mi], bb[ni], macc[mi][ni], 0, 0, 0);
    }
    const float inv = 1.0f / 4096.0f;
#pragma unroll
    for (int mi = 0; mi < 4; ++mi) {
      int p0 = pm * 64 + mi * 16 + lq * 4;
#pragma unroll
      for (int ni = 0; ni < 4; ++ni) {
        int il = im * 64 + ni * 16 + lm;
        unsigned short u0 = f2bf(macc[mi][ni][0] * inv);
        unsigned short u1 = f2bf(macc[mi][ni][1] * inv);
        unsigned short u2 = f2bf(macc[mi][ni][2] * inv);
        unsigned short u3 = f2bf(macc[mi][ni][3] * inv);
        uint2 o;
        o.x = (unsigned)u0 | ((unsigned)u1 << 16);
        o.y = (unsigned)u2 | ((unsigned)u3 << 16);
        *(uint2*)(W2L + ((il * 128 + p0) ^ ((il & 7) << 3))) = o;
      }
    }
  }
  __syncthreads();

  // main GEMM: C[128x128] = W2L @ TT^T ; epilogue + residual
  int wm = w >> 1, wn = w & 1;
  int cb = tn * 128 + wn * 64;
  int asw = (lm & 7) << 3;
  int aidx[4];
  const unsigned short* bp[4];
#pragma unroll
  for (int i = 0; i < 4; ++i) {
    aidx[i] = (wm * 64 + i * 16 + lm) * 128 + lq * 8;
    bp[i] = wsh + H_TT + (size_t)b * 524288 + (size_t)(cb + i * 16 + lm) * 128 + lq * 8;
  }
  f32x4 acc[4][4] = {};
  bf16x8 a0[4], b0[4];
#pragma unroll
  for (int i = 0; i < 4; ++i) {
    a0[i] = *(const bf16x8*)(W2L + (aidx[i] ^ asw));
    b0[i] = *(const bf16x8*)(bp[i]);
  }
  for (int k = 32; k < 128; k += 32) {
    bf16x8 a1[4], b1[4];
#pragma unroll
    for (int i = 0; i < 4; ++i) {
      a1[i] = *(const bf16x8*)(W2L + ((aidx[i] + k) ^ asw));
      b1[i] = *(const bf16x8*)(bp[i] + k);
    }
#pragma unroll
    for (int mi = 0; mi < 4; ++mi)
#pragma unroll
      for (int ni = 0; ni < 4; ++ni)
        acc[mi][ni] = __builtin_amdgcn_mfma_f32_16x16x32_bf16(a0[mi], b0[ni], acc[mi][ni], 0, 0, 0);
#pragma unroll
    for (int i = 0; i < 4; ++i) { a0[i] = a1[i]; b0[i] = b1[i]; }
  }
#pragma unroll
  for (int mi = 0; mi < 4; ++mi)
#pragma unroll
    for (int ni = 0; ni < 4; ++ni)
      acc[mi][ni] = __builtin_amdgcn_mfma_f32_16x16x32_bf16(a0[mi], b0[ni], acc[mi][ni], 0, 0, 0);

#pragma unroll
  for (int mi = 0; mi < 4; ++mi)
#pragma unroll
    for (int rr = 0; rr < 4; ++rr) {
      int row = rb + wm * 64 + mi * 16 + lq * 4 + rr;
      float bi = out_b[row];
#pragma unroll
      for (int ni = 0; ni < 4; ++ni) {
        int col = cb + ni * 16 + lm;
        size_t off = ((size_t)b * CC + row) * NSP + col;
        out[off] = acc[mi][ni][rr] + x[off] + bi;
      }
    }
}

extern "C" void kernel_launch(void* const* d_in, const int* in_sizes, int n_in,
                              void* d_out, int out_size, void* d_ws, size_t ws_size,
                              hipStream_t stream) {
  const float* x       = (const float*)d_in[0];
  const float* g_w     = (const float*)d_in[1];
  const float* g_b     = (const float*)d_in[2];
  const float* theta_w = (const float*)d_in[3];
  const float* theta_b = (const float*)d_in[4];
  const float* phi_w   = (const float*)d_in[5];
  const float* phi_b   = (const float*)d_in[6];
  const float* out_w   = (const float*)d_in[7];
  const float* out_b   = (const float*)d_in[8];
  float* wsf = (float*)d_ws;
  unsigned short* wsh = (unsigned short*)(wsf + F_WEND);
  float* out = (float*)d_out;

  kP<<<dim3(128), dim3(256), 0, stream>>>(g_w, theta_w, phi_w,
                                          g_b, theta_b, phi_b, x, wsh);
  kS<<<dim3(64), dim3(256), 0, stream>>>(wsh, wsf);
  kR<<<dim3(64), dim3(256), 0, stream>>>(wsf, wsh);
  kD<<<dim3(256), dim3(256), 0, stream>>>(wsh, out_w, x, out_b, out);
}

// Round 4
// 134.843 us; speedup vs baseline: 1.8386x; 1.0276x over previous
//
#include <hip/hip_runtime.h>
#include <hip/hip_bf16.h>

// Non-local block via rank-128 factorization:
//   G~ = g_w x + g_b ; T~ = theta_w x + theta_b ; P~ = phi_w x + phi_b   [128x4096]/batch
//   S''[p][g] = sum_n P~[p][n] G~[g][n]                                  [128x128]/batch
//   W2 = out_w @ S''^T / N                                               [256x128]/batch
//   out = x + W2 @ T~ + out_b
// 3 launches:
//  kP: fused transpose-in-LDS + 3 projections + LOCAL S'' partial (Yphi@Yg^T over this
//      block's 128-n slice, Y tiles spilled to LDS reusing XL) -> TT + fp32 partials
//  kR: reduce 32 partials/batch (coalesced) -> S'' bf16
//  kD: per-block W2 = out_w @ S''(_bt)/N into LDS (tiny) + out = x + W2@TT + out_b

#define CC   256
#define NSP  4096
#define NB   4
#define KSPLIT 32

typedef __attribute__((ext_vector_type(8))) short bf16x8;
typedef __attribute__((ext_vector_type(4))) float f32x4;

// fp32 region (float offsets from wsf): [4][32][128][128] S'' partials
#define F_WEND 2097152
// bf16 region (ushort offsets from wsh = wsf + F_WEND)
#define H_TT   0                    // [4][4096][128]  TT[n][p] = T~[p][n]
#define H_S2   2097152              // [4][128][128]   S'' bf16

__device__ __forceinline__ unsigned short f2bf(float f) {
  __hip_bfloat16 h = __float2bfloat16(f);
  return __builtin_bit_cast(unsigned short, h);
}
__device__ __forceinline__ uint4 pack8(const unsigned short* h) {
  uint4 u;
  u.x = (unsigned)h[0] | ((unsigned)h[1] << 16);
  u.y = (unsigned)h[2] | ((unsigned)h[3] << 16);
  u.z = (unsigned)h[4] | ((unsigned)h[5] << 16);
  u.w = (unsigned)h[6] | ((unsigned)h[7] << 16);
  return u;
}
// load 8 consecutive fp32, convert RNE -> bf16x8
__device__ __forceinline__ bf16x8 ld_cvt8(const float* __restrict__ p) {
  float4 lo = *(const float4*)p;
  float4 hi = *(const float4*)(p + 4);
  bf16x8 r;
  r[0] = (short)f2bf(lo.x); r[1] = (short)f2bf(lo.y);
  r[2] = (short)f2bf(lo.z); r[3] = (short)f2bf(lo.w);
  r[4] = (short)f2bf(hi.x); r[5] = (short)f2bf(hi.y);
  r[6] = (short)f2bf(hi.z); r[7] = (short)f2bf(hi.w);
  return r;
}

// ---- kP: fused X-transpose (LDS) + projections + local S'' partial ----
// grid 128 = 4 batches x 32 col-slices(128).
__global__ __launch_bounds__(256) void kP(
    const float* __restrict__ g_w, const float* __restrict__ theta_w,
    const float* __restrict__ phi_w, const float* __restrict__ g_b,
    const float* __restrict__ theta_b, const float* __restrict__ phi_b,
    const float* __restrict__ x, float* __restrict__ wsf,
    unsigned short* __restrict__ wsh) {
  __shared__ float T[64][65];
  __shared__ unsigned short XL[128 * 256];   // [n][k], idx ^= ((n&7)<<3); later: Yg|Yphi
  __shared__ float biasL[384];
  int bid = blockIdx.x;
  int b = bid >> 5, c = bid & 31;
  int t = threadIdx.x;
  if (t < 128) {
    biasL[t]       = g_b[t];
    biasL[128 + t] = theta_b[t];
    biasL[256 + t] = phi_b[t];
  }
  // ---- stage: 8 sub-tiles of 64x64 ----
  for (int s = 0; s < 8; ++s) {
    int kb = s >> 1, nb = s & 1;
    int r = t >> 2, j = t & 3;
    const float* xr = x + ((size_t)b * CC + kb * 64 + r) * NSP + c * 128 + nb * 64 + j * 16;
    float4 f0 = *(const float4*)(xr);
    float4 f1 = *(const float4*)(xr + 4);
    float4 f2 = *(const float4*)(xr + 8);
    float4 f3 = *(const float4*)(xr + 12);
    *(float4*)&T[r][j * 16 + 0]  = f0;
    *(float4*)&T[r][j * 16 + 4]  = f1;
    *(float4*)&T[r][j * 16 + 8]  = f2;
    *(float4*)&T[r][j * 16 + 12] = f3;
    __syncthreads();
    int nr = t >> 2, j2 = t & 3;
    unsigned short o[16];
#pragma unroll
    for (int i = 0; i < 16; ++i) o[i] = f2bf(T[j2 * 16 + i][nr]);
    int row = nb * 64 + nr;
    int kidx = kb * 64 + j2 * 16;
    int sw = (row & 7) << 3;
    *(uint4*)(XL + ((row * 256 + kidx) ^ sw))     = pack8(o);
    *(uint4*)(XL + ((row * 256 + kidx + 8) ^ sw)) = pack8(o + 8);
    __syncthreads();
  }

  // ---- projections ----
  int w = t >> 6, lane = t & 63;
  int wm = w >> 1, wn = w & 1;
  int lm = lane & 15, lq = lane >> 4;
  int bsw = (lm & 7) << 3;
  uint ygp[4][4][2];                 // Yg bf16-packed (bias added), this wave's quadrant
  uint ypp[4][4][2];                 // Yphi bf16-packed
#pragma unroll
  for (int r = 0; r < 3; ++r) {
    const float* wptr = (r == 0) ? g_w : (r == 1) ? theta_w : phi_w;
    const float* ap[4];
    int bidx[4];
#pragma unroll
    for (int i = 0; i < 4; ++i) {
      ap[i] = wptr + (size_t)(wm * 64 + i * 16 + lm) * CC + lq * 8;
      bidx[i] = (wn * 64 + i * 16 + lm) * 256 + lq * 8;
    }
    f32x4 acc[4][4] = {};
    bf16x8 a0[4], b0[4];
#pragma unroll
    for (int i = 0; i < 4; ++i) {
      a0[i] = ld_cvt8(ap[i]);
      b0[i] = *(const bf16x8*)(XL + (bidx[i] ^ bsw));
    }
    for (int k = 32; k < 256; k += 32) {
      bf16x8 a1[4], b1[4];
#pragma unroll
      for (int i = 0; i < 4; ++i) {
        a1[i] = ld_cvt8(ap[i] + k);
        b1[i] = *(const bf16x8*)(XL + ((bidx[i] + k) ^ bsw));
      }
#pragma unroll
      for (int mi = 0; mi < 4; ++mi)
#pragma unroll
        for (int ni = 0; ni < 4; ++ni)
          acc[mi][ni] = __builtin_amdgcn_mfma_f32_16x16x32_bf16(a0[mi], b0[ni], acc[mi][ni], 0, 0, 0);
#pragma unroll
      for (int i = 0; i < 4; ++i) { a0[i] = a1[i]; b0[i] = b1[i]; }
    }
#pragma unroll
    for (int mi = 0; mi < 4; ++mi)
#pragma unroll
      for (int ni = 0; ni < 4; ++ni)
        acc[mi][ni] = __builtin_amdgcn_mfma_f32_16x16x32_bf16(a0[mi], b0[ni], acc[mi][ni], 0, 0, 0);

    if (r == 1) {                    // theta: store transposed TT[n][p]
      size_t tb = (size_t)b * 524288;
#pragma unroll
      for (int mi = 0; mi < 4; ++mi) {
        int p0 = wm * 64 + mi * 16 + lq * 4;
#pragma unroll
        for (int ni = 0; ni < 4; ++ni) {
          int n = c * 128 + wn * 64 + ni * 16 + lm;
          unsigned short u0 = f2bf(acc[mi][ni][0] + biasL[128 + p0 + 0]);
          unsigned short u1 = f2bf(acc[mi][ni][1] + biasL[128 + p0 + 1]);
          unsigned short u2 = f2bf(acc[mi][ni][2] + biasL[128 + p0 + 2]);
          unsigned short u3 = f2bf(acc[mi][ni][3] + biasL[128 + p0 + 3]);
          uint2 o;
          o.x = (unsigned)u0 | ((unsigned)u1 << 16);
          o.y = (unsigned)u2 | ((unsigned)u3 << 16);
          *(uint2*)(wsh + H_TT + tb + (size_t)n * 128 + p0) = o;
        }
      }
    } else if (r == 0) {             // g: pack to regs (bias added)
#pragma unroll
      for (int mi = 0; mi < 4; ++mi) {
        int p0 = wm * 64 + mi * 16 + lq * 4;
#pragma unroll
        for (int ni = 0; ni < 4; ++ni) {
          unsigned short u0 = f2bf(acc[mi][ni][0] + biasL[p0 + 0]);
          unsigned short u1 = f2bf(acc[mi][ni][1] + biasL[p0 + 1]);
          unsigned short u2 = f2bf(acc[mi][ni][2] + biasL[p0 + 2]);
          unsigned short u3 = f2bf(acc[mi][ni][3] + biasL[p0 + 3]);
          ygp[mi][ni][0] = (unsigned)u0 | ((unsigned)u1 << 16);
          ygp[mi][ni][1] = (unsigned)u2 | ((unsigned)u3 << 16);
        }
      }
    } else {                         // phi: pack to regs (bias added)
#pragma unroll
      for (int mi = 0; mi < 4; ++mi) {
        int p0 = wm * 64 + mi * 16 + lq * 4;
#pragma unroll
        for (int ni = 0; ni < 4; ++ni) {
          unsigned short u0 = f2bf(acc[mi][ni][0] + biasL[256 + p0 + 0]);
          unsigned short u1 = f2bf(acc[mi][ni][1] + biasL[256 + p0 + 1]);
          unsigned short u2 = f2bf(acc[mi][ni][2] + biasL[256 + p0 + 2]);
          unsigned short u3 = f2bf(acc[mi][ni][3] + biasL[256 + p0 + 3]);
          ypp[mi][ni][0] = (unsigned)u0 | ((unsigned)u1 << 16);
          ypp[mi][ni][1] = (unsigned)u2 | ((unsigned)u3 << 16);
        }
      }
    }
  }

  // ---- spill Yg (XL[0:16384]) and Yphi (XL[16384:32768]) as [row][128n] swizzled ----
  __syncthreads();                   // all waves done reading XL
#pragma unroll
  for (int mi = 0; mi < 4; ++mi)
#pragma unroll
    for (int ni = 0; ni < 4; ++ni) {
      int n = wn * 64 + ni * 16 + lm;
#pragma unroll
      for (int rr = 0; rr < 4; ++rr) {
        int p = wm * 64 + mi * 16 + lq * 4 + rr;
        int phys = (p * 128 + n) ^ ((p & 7) << 3);
        XL[phys]         = (unsigned short)((ygp[mi][ni][rr >> 1] >> ((rr & 1) * 16)) & 0xFFFF);
        XL[16384 + phys] = (unsigned short)((ypp[mi][ni][rr >> 1] >> ((rr & 1) * 16)) & 0xFFFF);
      }
    }
  __syncthreads();

  // ---- local S'' partial: [p_phi 128 x g 128] over K=128 (this n-slice) ----
  {
    f32x4 sacc[4][4] = {};
    for (int k = 0; k < 128; k += 32) {
      bf16x8 af[4], bg[4];
#pragma unroll
      for (int i = 0; i < 4; ++i) {
        int ra = wm * 64 + i * 16 + lm;
        int rb2 = wn * 64 + i * 16 + lm;
        af[i] = *(const bf16x8*)(XL + 16384 + ((ra * 128 + lq * 8 + k) ^ ((ra & 7) << 3)));
        bg[i] = *(const bf16x8*)(XL + ((rb2 * 128 + lq * 8 + k) ^ ((rb2 & 7) << 3)));
      }
#pragma unroll
      for (int mi = 0; mi < 4; ++mi)
#pragma unroll
        for (int ni = 0; ni < 4; ++ni)
          sacc[mi][ni] = __builtin_amdgcn_mfma_f32_16x16x32_bf16(af[mi], bg[ni], sacc[mi][ni], 0, 0, 0);
    }
    float* P = wsf + (size_t)(b * KSPLIT + c) * 16384;
#pragma unroll
    for (int mi = 0; mi < 4; ++mi)
#pragma unroll
      for (int rr = 0; rr < 4; ++rr) {
        int p = wm * 64 + mi * 16 + lq * 4 + rr;
#pragma unroll
        for (int ni = 0; ni < 4; ++ni)
          P[p * 128 + wn * 64 + ni * 16 + lm] = sacc[mi][ni][rr];
      }
  }
}

// ---- kR: reduce partials -> S'' bf16. grid 64 = 4 batches x 16 slices ----
__global__ __launch_bounds__(256) void kR(const float* __restrict__ wsf,
                                          unsigned short* __restrict__ wsh) {
  int bid = blockIdx.x;
  int b = bid >> 4, e = bid & 15;
  int t = threadIdx.x;
  int base = e * 1024 + t * 4;
  const float* PB = wsf + (size_t)b * KSPLIT * 16384;
  float4 s = {0.f, 0.f, 0.f, 0.f};
#pragma unroll
  for (int ks = 0; ks < KSPLIT; ++ks) {
    float4 p = *(const float4*)(PB + (size_t)ks * 16384 + base);
    s.x += p.x; s.y += p.y; s.z += p.z; s.w += p.w;
  }
  uint2 o;
  o.x = (unsigned)f2bf(s.x) | ((unsigned)f2bf(s.y) << 16);
  o.y = (unsigned)f2bf(s.z) | ((unsigned)f2bf(s.w) << 16);
  *(uint2*)(wsh + H_S2 + (size_t)b * 16384 + base) = o;
}

// ---- kD: per-block W2 (K=128 mini-GEMM, into swizzled LDS) + out = x + W2@TT + out_b ----
__global__ __launch_bounds__(256) void kD(const unsigned short* __restrict__ wsh,
                                          const float* __restrict__ out_w,
                                          const float* __restrict__ x,
                                          const float* __restrict__ out_b,
                                          float* __restrict__ out) {
  __shared__ unsigned short W2L[128 * 128];  // [i_local][p], idx ^= ((i&7)<<3)
  int bid = blockIdx.x;
  int b = bid >> 6, r6 = bid & 63;
  int tm = r6 >> 5, tn = r6 & 31;
  int t = threadIdx.x, w = t >> 6, lane = t & 63;
  int lm = lane & 15, lq = lane >> 4;
  int rb = tm * 128;                 // global W2 row base for this block

  // mini-GEMM: W2^T tile per wave: A = S2 rows p, B = out_w rows i (cvt in-reg)
  {
    int pm = w >> 1, im = w & 1;
    const unsigned short* As = wsh + H_S2 + (size_t)b * 16384;
    f32x4 macc[4][4] = {};
    for (int kk = 0; kk < 128; kk += 32) {
      bf16x8 a[4], bb[4];
#pragma unroll
      for (int i = 0; i < 4; ++i) {
        a[i]  = *(const bf16x8*)(As + (size_t)(pm * 64 + i * 16 + lm) * 128 + lq * 8 + kk);
        bb[i] = ld_cvt8(out_w + (size_t)(rb + im * 64 + i * 16 + lm) * 128 + lq * 8 + kk);
      }
#pragma unroll
      for (int mi = 0; mi < 4; ++mi)
#pragma unroll
        for (int ni = 0; ni < 4; ++ni)
          macc[mi][ni] = __builtin_amdgcn_mfma_f32_16x16x32_bf16(a[mi], bb[ni], macc[mi][ni], 0, 0, 0);
    }
    const float inv = 1.0f / 4096.0f;
#pragma unroll
    for (int mi = 0; mi < 4; ++mi) {
      int p0 = pm * 64 + mi * 16 + lq * 4;
#pragma unroll
      for (int ni = 0; ni < 4; ++ni) {
        int il = im * 64 + ni * 16 + lm;
        unsigned short u0 = f2bf(macc[mi][ni][0] * inv);
        unsigned short u1 = f2bf(macc[mi][ni][1] * inv);
        unsigned short u2 = f2bf(macc[mi][ni][2] * inv);
        unsigned short u3 = f2bf(macc[mi][ni][3] * inv);
        uint2 o;
        o.x = (unsigned)u0 | ((unsigned)u1 << 16);
        o.y = (unsigned)u2 | ((unsigned)u3 << 16);
        *(uint2*)(W2L + ((il * 128 + p0) ^ ((il & 7) << 3))) = o;
      }
    }
  }
  __syncthreads();

  // main GEMM: C[128x128] = W2L @ TT^T ; epilogue + residual
  int wm = w >> 1, wn = w & 1;
  int cb = tn * 128 + wn * 64;
  int asw = (lm & 7) << 3;
  int aidx[4];
  const unsigned short* bp[4];
#pragma unroll
  for (int i = 0; i < 4; ++i) {
    aidx[i] = (wm * 64 + i * 16 + lm) * 128 + lq * 8;
    bp[i] = wsh + H_TT + (size_t)b * 524288 + (size_t)(cb + i * 16 + lm) * 128 + lq * 8;
  }
  f32x4 acc[4][4] = {};
  bf16x8 a0[4], b0[4];
#pragma unroll
  for (int i = 0; i < 4; ++i) {
    a0[i] = *(const bf16x8*)(W2L + (aidx[i] ^ asw));
    b0[i] = *(const bf16x8*)(bp[i]);
  }
  for (int k = 32; k < 128; k += 32) {
    bf16x8 a1[4], b1[4];
#pragma unroll
    for (int i = 0; i < 4; ++i) {
      a1[i] = *(const bf16x8*)(W2L + ((aidx[i] + k) ^ asw));
      b1[i] = *(const bf16x8*)(bp[i] + k);
    }
#pragma unroll
    for (int mi = 0; mi < 4; ++mi)
#pragma unroll
      for (int ni = 0; ni < 4; ++ni)
        acc[mi][ni] = __builtin_amdgcn_mfma_f32_16x16x32_bf16(a0[mi], b0[ni], acc[mi][ni], 0, 0, 0);
#pragma unroll
    for (int i = 0; i < 4; ++i) { a0[i] = a1[i]; b0[i] = b1[i]; }
  }
#pragma unroll
  for (int mi = 0; mi < 4; ++mi)
#pragma unroll
    for (int ni = 0; ni < 4; ++ni)
      acc[mi][ni] = __builtin_amdgcn_mfma_f32_16x16x32_bf16(a0[mi], b0[ni], acc[mi][ni], 0, 0, 0);

#pragma unroll
  for (int mi = 0; mi < 4; ++mi)
#pragma unroll
    for (int rr = 0; rr < 4; ++rr) {
      int row = rb + wm * 64 + mi * 16 + lq * 4 + rr;
      float bi = out_b[row];
#pragma unroll
      for (int ni = 0; ni < 4; ++ni) {
        int col = cb + ni * 16 + lm;
        size_t off = ((size_t)b * CC + row) * NSP + col;
        out[off] = acc[mi][ni][rr] + x[off] + bi;
      }
    }
}

extern "C" void kernel_launch(void* const* d_in, const int* in_sizes, int n_in,
                              void* d_out, int out_size, void* d_ws, size_t ws_size,
                              hipStream_t stream) {
  const float* x       = (const float*)d_in[0];
  const float* g_w     = (const float*)d_in[1];
  const float* g_b     = (const float*)d_in[2];
  const float* theta_w = (const float*)d_in[3];
  const float* theta_b = (const float*)d_in[4];
  const float* phi_w   = (const float*)d_in[5];
  const float* phi_b   = (const float*)d_in[6];
  const float* out_w   = (const float*)d_in[7];
  const float* out_b   = (const float*)d_in[8];
  float* wsf = (float*)d_ws;
  unsigned short* wsh = (unsigned short*)(wsf + F_WEND);
  float* out = (float*)d_out;

  kP<<<dim3(128), dim3(256), 0, stream>>>(g_w, theta_w, phi_w,
                                          g_b, theta_b, phi_b, x, wsf, wsh);
  kR<<<dim3(64), dim3(256), 0, stream>>>(wsf, wsh);
  kD<<<dim3(256), dim3(256), 0, stream>>>(wsh, out_w, x, out_b, out);
}

// Round 5
// 126.408 us; speedup vs baseline: 1.9613x; 1.0667x over previous
//
#include <hip/hip_runtime.h>
#include <hip/hip_bf16.h>

// Non-local block via rank-128 factorization:
//   G~ = g_w x + g_b ; T~ = theta_w x + theta_b ; P~ = phi_w x + phi_b   [128x4096]/batch
//   S''[p][g] = sum_n P~[p][n] G~[g][n]                                  [128x128]/batch
//   W2 = out_w @ S''^T / N                                               [256x128]/batch
//   out = x + W2 @ T~ + out_b
// 5 launches:
//  kW: weights fp32 -> bf16 (once; removes in-loop cvt from kP)
//  kP: grid 256 (4b x 64 n-slices): transpose-in-LDS + ONE k-sweep -> 3 projections
//      (shared B-frags, 3 acc sets) -> TT (theta, transposed) + PG (g/phi rows)
//  kS: split-K S'' partials from PG (grid 64, K=256 chunks) -> fp32 partials
//  kR: reduce 16 partials/batch -> S'' bf16
//  kD: per-block W2 = out_w @ S''(_bt)/N into LDS (tiny) + out = x + W2@TT + out_b

#define CC   256
#define NSP  4096
#define NB   4
#define KSPLIT 16

typedef __attribute__((ext_vector_type(8))) short bf16x8;
typedef __attribute__((ext_vector_type(4))) float f32x4;

// fp32 region (float offsets from wsf): [4][16][128][128] S'' partials
#define F_WEND 1048576
// bf16 region (ushort offsets from wsh = wsf + F_WEND)
#define H_TT   0                    // [4][4096][128]  TT[n][p] = T~[p][n]
#define H_PG   2097152              // [4][256][4096]  rows 0-127 = G~, 128-255 = P~
#define H_S2   6291456              // [4][128][128]   S'' bf16
#define H_WH   6356992              // [384][256] bf16 weights: g / theta / phi

__device__ __forceinline__ unsigned short f2bf(float f) {
  __hip_bfloat16 h = __float2bfloat16(f);
  return __builtin_bit_cast(unsigned short, h);
}
__device__ __forceinline__ uint4 pack8(const unsigned short* h) {
  uint4 u;
  u.x = (unsigned)h[0] | ((unsigned)h[1] << 16);
  u.y = (unsigned)h[2] | ((unsigned)h[3] << 16);
  u.z = (unsigned)h[4] | ((unsigned)h[5] << 16);
  u.w = (unsigned)h[6] | ((unsigned)h[7] << 16);
  return u;
}
// load 8 consecutive fp32, convert RNE -> bf16x8
__device__ __forceinline__ bf16x8 ld_cvt8(const float* __restrict__ p) {
  float4 lo = *(const float4*)p;
  float4 hi = *(const float4*)(p + 4);
  bf16x8 r;
  r[0] = (short)f2bf(lo.x); r[1] = (short)f2bf(lo.y);
  r[2] = (short)f2bf(lo.z); r[3] = (short)f2bf(lo.w);
  r[4] = (short)f2bf(hi.x); r[5] = (short)f2bf(hi.y);
  r[6] = (short)f2bf(hi.z); r[7] = (short)f2bf(hi.w);
  return r;
}

// Wave computes C[64x64] += A[64xK] * B^T[64xK] (bf16 row-major, K contiguous), 1-deep prefetch.
__device__ __forceinline__ void wave_gemm_bt(const unsigned short* __restrict__ A, int pitchA,
                                             const unsigned short* __restrict__ B, int pitchB,
                                             int K, int lane, f32x4 acc[4][4]) {
  int lm = lane & 15, lq = lane >> 4;
  const unsigned short* ap[4];
  const unsigned short* bp[4];
#pragma unroll
  for (int i = 0; i < 4; ++i) {
    ap[i] = A + (size_t)(i * 16 + lm) * pitchA + lq * 8;
    bp[i] = B + (size_t)(i * 16 + lm) * pitchB + lq * 8;
  }
  bf16x8 a0[4], b0[4];
#pragma unroll
  for (int i = 0; i < 4; ++i) {
    a0[i] = *(const bf16x8*)(ap[i]);
    b0[i] = *(const bf16x8*)(bp[i]);
  }
  for (int k = 32; k < K; k += 32) {
    bf16x8 a1[4], b1[4];
#pragma unroll
    for (int i = 0; i < 4; ++i) {
      a1[i] = *(const bf16x8*)(ap[i] + k);
      b1[i] = *(const bf16x8*)(bp[i] + k);
    }
#pragma unroll
    for (int mi = 0; mi < 4; ++mi)
#pragma unroll
      for (int ni = 0; ni < 4; ++ni)
        acc[mi][ni] = __builtin_amdgcn_mfma_f32_16x16x32_bf16(a0[mi], b0[ni], acc[mi][ni], 0, 0, 0);
#pragma unroll
    for (int i = 0; i < 4; ++i) { a0[i] = a1[i]; b0[i] = b1[i]; }
  }
#pragma unroll
  for (int mi = 0; mi < 4; ++mi)
#pragma unroll
    for (int ni = 0; ni < 4; ++ni)
      acc[mi][ni] = __builtin_amdgcn_mfma_f32_16x16x32_bf16(a0[mi], b0[ni], acc[mi][ni], 0, 0, 0);
}

// ---- kW: weights fp32 -> bf16 stack [g; theta; phi] ----
__global__ __launch_bounds__(256) void kW(const float* __restrict__ g_w,
                                          const float* __restrict__ theta_w,
                                          const float* __restrict__ phi_w,
                                          unsigned short* __restrict__ wsh) {
  int idx = (blockIdx.x * 256 + threadIdx.x) * 4;   // over 98304 els
  int r = idx >> 8;
  const float* src = (r < 128) ? (g_w + idx)
                   : (r < 256) ? (theta_w + idx - 32768)
                               : (phi_w + idx - 65536);
  float4 v = *(const float4*)src;
  uint2 o;
  o.x = (unsigned)f2bf(v.x) | ((unsigned)f2bf(v.y) << 16);
  o.y = (unsigned)f2bf(v.z) | ((unsigned)f2bf(v.w) << 16);
  *(uint2*)(wsh + H_WH + idx) = o;
}

// ---- kP: fused X-transpose (LDS) + single-sweep 3 projections ----
// grid 256 = 4 batches x 64 col-slices(64n).
__global__ __launch_bounds__(256) void kP(
    const float* __restrict__ g_b, const float* __restrict__ theta_b,
    const float* __restrict__ phi_b, const float* __restrict__ x,
    unsigned short* __restrict__ wsh) {
  __shared__ float T[64][65];
  __shared__ unsigned short XL[64 * 256];    // [n][k], idx ^= ((n&7)<<3)
  __shared__ float biasL[384];
  int bid = blockIdx.x;
  int b = bid >> 6, c = bid & 63;
  int t = threadIdx.x;
  if (t < 128) {
    biasL[t]       = g_b[t];
    biasL[128 + t] = theta_b[t];
    biasL[256 + t] = phi_b[t];
  }
  // ---- stage: 4 sub-tiles of 64k x 64n ----
  for (int s = 0; s < 4; ++s) {
    int r = t >> 2, j = t & 3;
    const float* xr = x + ((size_t)b * CC + s * 64 + r) * NSP + c * 64 + j * 16;
    float4 f0 = *(const float4*)(xr);
    float4 f1 = *(const float4*)(xr + 4);
    float4 f2 = *(const float4*)(xr + 8);
    float4 f3 = *(const float4*)(xr + 12);
    *(float4*)&T[r][j * 16 + 0]  = f0;
    *(float4*)&T[r][j * 16 + 4]  = f1;
    *(float4*)&T[r][j * 16 + 8]  = f2;
    *(float4*)&T[r][j * 16 + 12] = f3;
    __syncthreads();
    int nr = t >> 2, j2 = t & 3;
    unsigned short o[16];
#pragma unroll
    for (int i = 0; i < 16; ++i) o[i] = f2bf(T[j2 * 16 + i][nr]);
    int kidx = s * 64 + j2 * 16;
    int sw = (nr & 7) << 3;
    *(uint4*)(XL + ((nr * 256 + kidx) ^ sw))     = pack8(o);
    *(uint4*)(XL + ((nr * 256 + kidx + 8) ^ sw)) = pack8(o + 8);
    __syncthreads();
  }

  // ---- one k-sweep, 3 projections (shared B-frags) ----
  int w = t >> 6, lane = t & 63;
  int wm = w >> 1, wn = w & 1;
  int lm = lane & 15, lq = lane >> 4;
  int bsw = (lm & 7) << 3;
  const unsigned short* aw[4];
  int bidx[2];
#pragma unroll
  for (int i = 0; i < 4; ++i)
    aw[i] = wsh + H_WH + (size_t)(wm * 64 + i * 16 + lm) * 256 + lq * 8;
#pragma unroll
  for (int j = 0; j < 2; ++j)
    bidx[j] = (wn * 32 + j * 16 + lm) * 256 + lq * 8;

  f32x4 ag[4][2] = {}, at2[4][2] = {}, ap2[4][2] = {};
#pragma unroll 2
  for (int k = 0; k < 256; k += 32) {
    bf16x8 bb[2], xg[4], xt[4], xp[4];
#pragma unroll
    for (int j = 0; j < 2; ++j) bb[j] = *(const bf16x8*)(XL + ((bidx[j] + k) ^ bsw));
#pragma unroll
    for (int i = 0; i < 4; ++i) {
      xg[i] = *(const bf16x8*)(aw[i] + k);
      xt[i] = *(const bf16x8*)(aw[i] + 32768 + k);
      xp[i] = *(const bf16x8*)(aw[i] + 65536 + k);
    }
#pragma unroll
    for (int mi = 0; mi < 4; ++mi)
#pragma unroll
      for (int ni = 0; ni < 2; ++ni) {
        ag[mi][ni]  = __builtin_amdgcn_mfma_f32_16x16x32_bf16(xg[mi], bb[ni], ag[mi][ni], 0, 0, 0);
        at2[mi][ni] = __builtin_amdgcn_mfma_f32_16x16x32_bf16(xt[mi], bb[ni], at2[mi][ni], 0, 0, 0);
        ap2[mi][ni] = __builtin_amdgcn_mfma_f32_16x16x32_bf16(xp[mi], bb[ni], ap2[mi][ni], 0, 0, 0);
      }
  }

  // ---- stores ----
  size_t tb = (size_t)b * 524288;
  size_t pbo = (size_t)b * 1048576;
#pragma unroll
  for (int mi = 0; mi < 4; ++mi) {
    int p0 = wm * 64 + mi * 16 + lq * 4;
#pragma unroll
    for (int ni = 0; ni < 2; ++ni) {
      int n = c * 64 + wn * 32 + ni * 16 + lm;
      // theta -> TT[n][p] (transposed, packed)
      unsigned short u0 = f2bf(at2[mi][ni][0] + biasL[128 + p0 + 0]);
      unsigned short u1 = f2bf(at2[mi][ni][1] + biasL[128 + p0 + 1]);
      unsigned short u2 = f2bf(at2[mi][ni][2] + biasL[128 + p0 + 2]);
      unsigned short u3 = f2bf(at2[mi][ni][3] + biasL[128 + p0 + 3]);
      uint2 o;
      o.x = (unsigned)u0 | ((unsigned)u1 << 16);
      o.y = (unsigned)u2 | ((unsigned)u3 << 16);
      *(uint2*)(wsh + H_TT + tb + (size_t)n * 128 + p0) = o;
      // g / phi -> PG rows
#pragma unroll
      for (int rr = 0; rr < 4; ++rr) {
        int pl = p0 + rr;
        wsh[H_PG + pbo + (size_t)pl * NSP + n]         = f2bf(ag[mi][ni][rr] + biasL[pl]);
        wsh[H_PG + pbo + (size_t)(128 + pl) * NSP + n] = f2bf(ap2[mi][ni][rr] + biasL[256 + pl]);
      }
    }
  }
}

// ---- kS: split-K S'' partials. grid = 4 batches x 16 chunks (K=256 each) ----
__global__ __launch_bounds__(256) void kS(const unsigned short* __restrict__ wsh,
                                          float* __restrict__ wsf) {
  int bid = blockIdx.x;
  int b = bid >> 4, ks = bid & 15;
  int t = threadIdx.x, w = t >> 6, lane = t & 63;
  int lm = lane & 15, lq = lane >> 4;
  int qm = w >> 1, qn = w & 1;
  const unsigned short* A = wsh + H_PG + (size_t)b * 1048576 +
                            (size_t)(128 + qm * 64) * NSP + ks * 256;
  const unsigned short* B = wsh + H_PG + (size_t)b * 1048576 +
                            (size_t)(qn * 64) * NSP + ks * 256;
  f32x4 acc[4][4] = {};
  wave_gemm_bt(A, NSP, B, NSP, 256, lane, acc);
  float* P = wsf + (size_t)(b * KSPLIT + ks) * 16384;
#pragma unroll
  for (int mi = 0; mi < 4; ++mi)
#pragma unroll
    for (int rr = 0; rr < 4; ++rr) {
      int p = qm * 64 + mi * 16 + lq * 4 + rr;
#pragma unroll
      for (int ni = 0; ni < 4; ++ni)
        P[p * 128 + qn * 64 + ni * 16 + lm] = acc[mi][ni][rr];
    }
}

// ---- kR: reduce partials -> S'' bf16. grid 64 = 4 batches x 16 slices ----
__global__ __launch_bounds__(256) void kR(const float* __restrict__ wsf,
                                          unsigned short* __restrict__ wsh) {
  int bid = blockIdx.x;
  int b = bid >> 4, e = bid & 15;
  int t = threadIdx.x;
  int base = e * 1024 + t * 4;
  const float* PB = wsf + (size_t)b * KSPLIT * 16384;
  float4 s = {0.f, 0.f, 0.f, 0.f};
#pragma unroll
  for (int ks = 0; ks < KSPLIT; ++ks) {
    float4 p = *(const float4*)(PB + (size_t)ks * 16384 + base);
    s.x += p.x; s.y += p.y; s.z += p.z; s.w += p.w;
  }
  uint2 o;
  o.x = (unsigned)f2bf(s.x) | ((unsigned)f2bf(s.y) << 16);
  o.y = (unsigned)f2bf(s.z) | ((unsigned)f2bf(s.w) << 16);
  *(uint2*)(wsh + H_S2 + (size_t)b * 16384 + base) = o;
}

// ---- kD: per-block W2 (K=128 mini-GEMM, into swizzled LDS) + out = x + W2@TT + out_b ----
__global__ __launch_bounds__(256) void kD(const unsigned short* __restrict__ wsh,
                                          const float* __restrict__ out_w,
                                          const float* __restrict__ x,
                                          const float* __restrict__ out_b,
                                          float* __restrict__ out) {
  __shared__ unsigned short W2L[128 * 128];  // [i_local][p], idx ^= ((i&7)<<3)
  int bid = blockIdx.x;
  int b = bid >> 6, r6 = bid & 63;
  int tm = r6 >> 5, tn = r6 & 31;
  int t = threadIdx.x, w = t >> 6, lane = t & 63;
  int lm = lane & 15, lq = lane >> 4;
  int rb = tm * 128;                 // global W2 row base for this block

  // mini-GEMM: W2^T tile per wave: A = S2 rows p, B = out_w rows i (cvt in-reg)
  {
    int pm = w >> 1, im = w & 1;
    const unsigned short* As = wsh + H_S2 + (size_t)b * 16384;
    f32x4 macc[4][4] = {};
    for (int kk = 0; kk < 128; kk += 32) {
      bf16x8 a[4], bb[4];
#pragma unroll
      for (int i = 0; i < 4; ++i) {
        a[i]  = *(const bf16x8*)(As + (size_t)(pm * 64 + i * 16 + lm) * 128 + lq * 8 + kk);
        bb[i] = ld_cvt8(out_w + (size_t)(rb + im * 64 + i * 16 + lm) * 128 + lq * 8 + kk);
      }
#pragma unroll
      for (int mi = 0; mi < 4; ++mi)
#pragma unroll
        for (int ni = 0; ni < 4; ++ni)
          macc[mi][ni] = __builtin_amdgcn_mfma_f32_16x16x32_bf16(a[mi], bb[ni], macc[mi][ni], 0, 0, 0);
    }
    const float inv = 1.0f / 4096.0f;
#pragma unroll
    for (int mi = 0; mi < 4; ++mi) {
      int p0 = pm * 64 + mi * 16 + lq * 4;
#pragma unroll
      for (int ni = 0; ni < 4; ++ni) {
        int il = im * 64 + ni * 16 + lm;
        unsigned short u0 = f2bf(macc[mi][ni][0] * inv);
        unsigned short u1 = f2bf(macc[mi][ni][1] * inv);
        unsigned short u2 = f2bf(macc[mi][ni][2] * inv);
        unsigned short u3 = f2bf(macc[mi][ni][3] * inv);
        uint2 o;
        o.x = (unsigned)u0 | ((unsigned)u1 << 16);
        o.y = (unsigned)u2 | ((unsigned)u3 << 16);
        *(uint2*)(W2L + ((il * 128 + p0) ^ ((il & 7) << 3))) = o;
      }
    }
  }
  __syncthreads();

  // main GEMM: C[128x128] = W2L @ TT^T ; epilogue + residual
  int wm = w >> 1, wn = w & 1;
  int cb = tn * 128 + wn * 64;
  int asw = (lm & 7) << 3;
  int aidx[4];
  const unsigned short* bp[4];
#pragma unroll
  for (int i = 0; i < 4; ++i) {
    aidx[i] = (wm * 64 + i * 16 + lm) * 128 + lq * 8;
    bp[i] = wsh + H_TT + (size_t)b * 524288 + (size_t)(cb + i * 16 + lm) * 128 + lq * 8;
  }
  f32x4 acc[4][4] = {};
  bf16x8 a0[4], b0[4];
#pragma unroll
  for (int i = 0; i < 4; ++i) {
    a0[i] = *(const bf16x8*)(W2L + (aidx[i] ^ asw));
    b0[i] = *(const bf16x8*)(bp[i]);
  }
  for (int k = 32; k < 128; k += 32) {
    bf16x8 a1[4], b1[4];
#pragma unroll
    for (int i = 0; i < 4; ++i) {
      a1[i] = *(const bf16x8*)(W2L + ((aidx[i] + k) ^ asw));
      b1[i] = *(const bf16x8*)(bp[i] + k);
    }
#pragma unroll
    for (int mi = 0; mi < 4; ++mi)
#pragma unroll
      for (int ni = 0; ni < 4; ++ni)
        acc[mi][ni] = __builtin_amdgcn_mfma_f32_16x16x32_bf16(a0[mi], b0[ni], acc[mi][ni], 0, 0, 0);
#pragma unroll
    for (int i = 0; i < 4; ++i) { a0[i] = a1[i]; b0[i] = b1[i]; }
  }
#pragma unroll
  for (int mi = 0; mi < 4; ++mi)
#pragma unroll
    for (int ni = 0; ni < 4; ++ni)
      acc[mi][ni] = __builtin_amdgcn_mfma_f32_16x16x32_bf16(a0[mi], b0[ni], acc[mi][ni], 0, 0, 0);

#pragma unroll
  for (int mi = 0; mi < 4; ++mi)
#pragma unroll
    for (int rr = 0; rr < 4; ++rr) {
      int row = rb + wm * 64 + mi * 16 + lq * 4 + rr;
      float bi = out_b[row];
#pragma unroll
      for (int ni = 0; ni < 4; ++ni) {
        int col = cb + ni * 16 + lm;
        size_t off = ((size_t)b * CC + row) * NSP + col;
        out[off] = acc[mi][ni][rr] + x[off] + bi;
      }
    }
}

extern "C" void kernel_launch(void* const* d_in, const int* in_sizes, int n_in,
                              void* d_out, int out_size, void* d_ws, size_t ws_size,
                              hipStream_t stream) {
  const float* x       = (const float*)d_in[0];
  const float* g_w     = (const float*)d_in[1];
  const float* g_b     = (const float*)d_in[2];
  const float* theta_w = (const float*)d_in[3];
  const float* theta_b = (const float*)d_in[4];
  const float* phi_w   = (const float*)d_in[5];
  const float* phi_b   = (const float*)d_in[6];
  const float* out_w   = (const float*)d_in[7];
  const float* out_b   = (const float*)d_in[8];
  float* wsf = (float*)d_ws;
  unsigned short* wsh = (unsigned short*)(wsf + F_WEND);
  float* out = (float*)d_out;

  kW<<<dim3(96), dim3(256), 0, stream>>>(g_w, theta_w, phi_w, wsh);
  kP<<<dim3(256), dim3(256), 0, stream>>>(g_b, theta_b, phi_b, x, wsh);
  kS<<<dim3(64), dim3(256), 0, stream>>>(wsh, wsf);
  kR<<<dim3(64), dim3(256), 0, stream>>>(wsf, wsh);
  kD<<<dim3(256), dim3(256), 0, stream>>>(wsh, out_w, x, out_b, out);
}

// Round 6
// 125.245 us; speedup vs baseline: 1.9795x; 1.0093x over previous
//
#include <hip/hip_runtime.h>
#include <hip/hip_bf16.h>

// Non-local block via rank-128 factorization:
//   G~ = g_w x + g_b ; T~ = theta_w x + theta_b ; P~ = phi_w x + phi_b   [128x4096]/batch
//   S''[p][g] = sum_n P~[p][n] G~[g][n]                                  [128x128]/batch
//   W2 = out_w @ S''^T / N                                               [256x128]/batch
//   out = x + W2 @ T~ + out_b
// 6 launches:
//  kW:  weights fp32 -> bf16 (g/theta/phi stack + out_w)
//  kP:  grid 512 (4b x 128 n-slices of 32): transpose-in-LDS + one k-sweep -> 3 proj;
//       TT (theta transposed), g/phi re-staged via LDS -> coalesced PG rows
//  kS:  split-K S'' partials from PG (grid 64, K=256 chunks) -> fp32 partials
//  kR:  reduce 16 partials/batch -> S'' bf16
//  kW2: W2 = out_w @ S''(_bt) / N -> bf16 (grid 16)
//  kD:  LDS-free stream GEMM: out = x + W2 @ TT(_bt) + out_b (grid 512)

#define CC   256
#define NSP  4096
#define NB   4
#define KSPLIT 16

typedef __attribute__((ext_vector_type(8))) short bf16x8;
typedef __attribute__((ext_vector_type(4))) float f32x4;

// fp32 region (float offsets from wsf): [4][16][128][128] S'' partials
#define F_WEND 1048576
// bf16 region (ushort offsets from wsh = wsf + F_WEND)
#define H_TT   0                    // [4][4096][128]  TT[n][p] = T~[p][n]
#define H_PG   2097152              // [4][256][4096]  rows 0-127 = G~, 128-255 = P~
#define H_S2   6291456              // [4][128][128]   S'' bf16
#define H_WH   6356992              // [384][256] bf16 weights: g / theta / phi
#define H_OWH  6455296              // [256][128] bf16 out_w
#define H_W2   6488064              // [4][256][128] bf16 W2

__device__ __forceinline__ unsigned short f2bf(float f) {
  __hip_bfloat16 h = __float2bfloat16(f);
  return __builtin_bit_cast(unsigned short, h);
}
__device__ __forceinline__ uint4 pack8(const unsigned short* h) {
  uint4 u;
  u.x = (unsigned)h[0] | ((unsigned)h[1] << 16);
  u.y = (unsigned)h[2] | ((unsigned)h[3] << 16);
  u.z = (unsigned)h[4] | ((unsigned)h[5] << 16);
  u.w = (unsigned)h[6] | ((unsigned)h[7] << 16);
  return u;
}

// Wave computes C[64x64] += A[64xK] * B^T[64xK] (bf16 row-major, K contiguous), 1-deep prefetch.
__device__ __forceinline__ void wave_gemm_bt(const unsigned short* __restrict__ A, int pitchA,
                                             const unsigned short* __restrict__ B, int pitchB,
                                             int K, int lane, f32x4 acc[4][4]) {
  int lm = lane & 15, lq = lane >> 4;
  const unsigned short* ap[4];
  const unsigned short* bp[4];
#pragma unroll
  for (int i = 0; i < 4; ++i) {
    ap[i] = A + (size_t)(i * 16 + lm) * pitchA + lq * 8;
    bp[i] = B + (size_t)(i * 16 + lm) * pitchB + lq * 8;
  }
  bf16x8 a0[4], b0[4];
#pragma unroll
  for (int i = 0; i < 4; ++i) {
    a0[i] = *(const bf16x8*)(ap[i]);
    b0[i] = *(const bf16x8*)(bp[i]);
  }
  for (int k = 32; k < K; k += 32) {
    bf16x8 a1[4], b1[4];
#pragma unroll
    for (int i = 0; i < 4; ++i) {
      a1[i] = *(const bf16x8*)(ap[i] + k);
      b1[i] = *(const bf16x8*)(bp[i] + k);
    }
#pragma unroll
    for (int mi = 0; mi < 4; ++mi)
#pragma unroll
      for (int ni = 0; ni < 4; ++ni)
        acc[mi][ni] = __builtin_amdgcn_mfma_f32_16x16x32_bf16(a0[mi], b0[ni], acc[mi][ni], 0, 0, 0);
#pragma unroll
    for (int i = 0; i < 4; ++i) { a0[i] = a1[i]; b0[i] = b1[i]; }
  }
#pragma unroll
  for (int mi = 0; mi < 4; ++mi)
#pragma unroll
    for (int ni = 0; ni < 4; ++ni)
      acc[mi][ni] = __builtin_amdgcn_mfma_f32_16x16x32_bf16(a0[mi], b0[ni], acc[mi][ni], 0, 0, 0);
}

// ---- kW: weights fp32 -> bf16: [g; theta; phi] stack + out_w. grid 128 ----
__global__ __launch_bounds__(256) void kW(const float* __restrict__ g_w,
                                          const float* __restrict__ theta_w,
                                          const float* __restrict__ phi_w,
                                          const float* __restrict__ out_w,
                                          unsigned short* __restrict__ wsh) {
  int idx = (blockIdx.x * 256 + threadIdx.x) * 4;   // over 131072 els
  const float* src;
  unsigned short* dst;
  if (idx < 98304) {
    int r = idx >> 8;
    src = (r < 128) ? (g_w + idx)
        : (r < 256) ? (theta_w + idx - 32768)
                    : (phi_w + idx - 65536);
    dst = wsh + H_WH + idx;
  } else {
    src = out_w + (idx - 98304);
    dst = wsh + H_OWH + (idx - 98304);
  }
  float4 v = *(const float4*)src;
  uint2 o;
  o.x = (unsigned)f2bf(v.x) | ((unsigned)f2bf(v.y) << 16);
  o.y = (unsigned)f2bf(v.z) | ((unsigned)f2bf(v.w) << 16);
  *(uint2*)dst = o;
}

// ---- kP: fused X-transpose (LDS) + single-sweep 3 projections ----
// grid 512 = 4 batches x 128 col-slices(32n). ~26 KB LDS -> 2 blocks/CU.
__global__ __launch_bounds__(256) void kP(
    const float* __restrict__ g_b, const float* __restrict__ theta_b,
    const float* __restrict__ phi_b, const float* __restrict__ x,
    unsigned short* __restrict__ wsh) {
  __shared__ float T[64][33];
  __shared__ unsigned short XL[32 * 256];    // [n][k], idx ^= ((n&7)<<3); later Y re-stage
  __shared__ float biasL[384];
  int bid = blockIdx.x;
  int b = bid >> 7, c = bid & 127;
  int t = threadIdx.x;
  if (t < 128) {
    biasL[t]       = g_b[t];
    biasL[128 + t] = theta_b[t];
    biasL[256 + t] = phi_b[t];
  }
  // ---- stage: 4 rounds of 64k x 32n ----
  for (int s = 0; s < 4; ++s) {
    int r = t >> 2, j = t & 3;
    const float* xr = x + ((size_t)b * CC + s * 64 + r) * NSP + c * 32 + j * 8;
    float4 f0 = *(const float4*)(xr);
    float4 f1 = *(const float4*)(xr + 4);
    T[r][j * 8 + 0] = f0.x; T[r][j * 8 + 1] = f0.y;
    T[r][j * 8 + 2] = f0.z; T[r][j * 8 + 3] = f0.w;
    T[r][j * 8 + 4] = f1.x; T[r][j * 8 + 5] = f1.y;
    T[r][j * 8 + 6] = f1.z; T[r][j * 8 + 7] = f1.w;
    __syncthreads();
    int nr = t >> 3, j2 = t & 7;
    unsigned short o[8];
#pragma unroll
    for (int i = 0; i < 8; ++i) o[i] = f2bf(T[j2 * 8 + i][nr]);
    int kidx = s * 64 + j2 * 8;
    int sw = (nr & 7) << 3;
    *(uint4*)(XL + ((nr * 256 + kidx) ^ sw)) = pack8(o);
    __syncthreads();
  }

  // ---- one k-sweep, 3 projections (shared B-frags); wave w owns p-rows [w*32, w*32+32) ----
  int w = t >> 6, lane = t & 63;
  int lm = lane & 15, lq = lane >> 4;
  int bsw = (lm & 7) << 3;
  const unsigned short* aw[2];
  int bidx[2];
#pragma unroll
  for (int i = 0; i < 2; ++i)
    aw[i] = wsh + H_WH + (size_t)(w * 32 + i * 16 + lm) * 256 + lq * 8;
#pragma unroll
  for (int j = 0; j < 2; ++j)
    bidx[j] = (j * 16 + lm) * 256 + lq * 8;

  f32x4 ag[2][2] = {}, at2[2][2] = {}, ap2[2][2] = {};
#pragma unroll 2
  for (int k = 0; k < 256; k += 32) {
    bf16x8 bb[2], xg[2], xt[2], xp[2];
#pragma unroll
    for (int j = 0; j < 2; ++j) bb[j] = *(const bf16x8*)(XL + ((bidx[j] + k) ^ bsw));
#pragma unroll
    for (int i = 0; i < 2; ++i) {
      xg[i] = *(const bf16x8*)(aw[i] + k);
      xt[i] = *(const bf16x8*)(aw[i] + 32768 + k);
      xp[i] = *(const bf16x8*)(aw[i] + 65536 + k);
    }
#pragma unroll
    for (int mi = 0; mi < 2; ++mi)
#pragma unroll
      for (int ni = 0; ni < 2; ++ni) {
        ag[mi][ni]  = __builtin_amdgcn_mfma_f32_16x16x32_bf16(xg[mi], bb[ni], ag[mi][ni], 0, 0, 0);
        at2[mi][ni] = __builtin_amdgcn_mfma_f32_16x16x32_bf16(xt[mi], bb[ni], at2[mi][ni], 0, 0, 0);
        ap2[mi][ni] = __builtin_amdgcn_mfma_f32_16x16x32_bf16(xp[mi], bb[ni], ap2[mi][ni], 0, 0, 0);
      }
  }

  // ---- TT store (theta, transposed, packed uint2) ----
  size_t tb = (size_t)b * 524288;
#pragma unroll
  for (int mi = 0; mi < 2; ++mi) {
    int p0 = w * 32 + mi * 16 + lq * 4;
#pragma unroll
    for (int ni = 0; ni < 2; ++ni) {
      int n = c * 32 + ni * 16 + lm;
      unsigned short u0 = f2bf(at2[mi][ni][0] + biasL[128 + p0 + 0]);
      unsigned short u1 = f2bf(at2[mi][ni][1] + biasL[128 + p0 + 1]);
      unsigned short u2 = f2bf(at2[mi][ni][2] + biasL[128 + p0 + 2]);
      unsigned short u3 = f2bf(at2[mi][ni][3] + biasL[128 + p0 + 3]);
      uint2 o;
      o.x = (unsigned)u0 | ((unsigned)u1 << 16);
      o.y = (unsigned)u2 | ((unsigned)u3 << 16);
      *(uint2*)(wsh + H_TT + tb + (size_t)n * 128 + p0) = o;
    }
  }

  // ---- re-stage g/phi into XL [256 rows][32 n] then coalesced PG store ----
  __syncthreads();                   // all waves done reading XL
#pragma unroll
  for (int mi = 0; mi < 2; ++mi)
#pragma unroll
    for (int ni = 0; ni < 2; ++ni) {
      int nl = ni * 16 + lm;
#pragma unroll
      for (int rr = 0; rr < 4; ++rr) {
        int p = w * 32 + mi * 16 + lq * 4 + rr;
        XL[p * 32 + nl]         = f2bf(ag[mi][ni][rr] + biasL[p]);
        XL[(128 + p) * 32 + nl] = f2bf(ap2[mi][ni][rr] + biasL[256 + p]);
      }
    }
  __syncthreads();
  size_t pbo = (size_t)b * 1048576;
#pragma unroll
  for (int r4 = 0; r4 < 4; ++r4) {
    int row = r4 * 64 + (t >> 2);
    int coff = (t & 3) * 8;
    *(uint4*)(wsh + H_PG + pbo + (size_t)row * NSP + c * 32 + coff) =
        *(uint4*)(XL + row * 32 + coff);
  }
}

// ---- kS: split-K S'' partials. grid = 4 batches x 16 chunks (K=256 each) ----
__global__ __launch_bounds__(256) void kS(const unsigned short* __restrict__ wsh,
                                          float* __restrict__ wsf) {
  int bid = blockIdx.x;
  int b = bid >> 4, ks = bid & 15;
  int t = threadIdx.x, w = t >> 6, lane = t & 63;
  int lm = lane & 15, lq = lane >> 4;
  int qm = w >> 1, qn = w & 1;
  const unsigned short* A = wsh + H_PG + (size_t)b * 1048576 +
                            (size_t)(128 + qm * 64) * NSP + ks * 256;
  const unsigned short* B = wsh + H_PG + (size_t)b * 1048576 +
                            (size_t)(qn * 64) * NSP + ks * 256;
  f32x4 acc[4][4] = {};
  wave_gemm_bt(A, NSP, B, NSP, 256, lane, acc);
  float* P = wsf + (size_t)(b * KSPLIT + ks) * 16384;
#pragma unroll
  for (int mi = 0; mi < 4; ++mi)
#pragma unroll
    for (int rr = 0; rr < 4; ++rr) {
      int p = qm * 64 + mi * 16 + lq * 4 + rr;
#pragma unroll
      for (int ni = 0; ni < 4; ++ni)
        P[p * 128 + qn * 64 + ni * 16 + lm] = acc[mi][ni][rr];
    }
}

// ---- kR: reduce partials -> S'' bf16. grid 64 = 4 batches x 16 slices ----
__global__ __launch_bounds__(256) void kR(const float* __restrict__ wsf,
                                          unsigned short* __restrict__ wsh) {
  int bid = blockIdx.x;
  int b = bid >> 4, e = bid & 15;
  int t = threadIdx.x;
  int base = e * 1024 + t * 4;
  const float* PB = wsf + (size_t)b * KSPLIT * 16384;
  float4 s = {0.f, 0.f, 0.f, 0.f};
#pragma unroll
  for (int ks = 0; ks < KSPLIT; ++ks) {
    float4 p = *(const float4*)(PB + (size_t)ks * 16384 + base);
    s.x += p.x; s.y += p.y; s.z += p.z; s.w += p.w;
  }
  uint2 o;
  o.x = (unsigned)f2bf(s.x) | ((unsigned)f2bf(s.y) << 16);
  o.y = (unsigned)f2bf(s.z) | ((unsigned)f2bf(s.w) << 16);
  *(uint2*)(wsh + H_S2 + (size_t)b * 16384 + base) = o;
}

// ---- kW2: W2[i][p] = sum_g out_w[i][g] S''[p][g] / N. grid 16 = 4b x 4 i-slices ----
__global__ __launch_bounds__(256) void kW2(unsigned short* __restrict__ wsh) {
  int bid = blockIdx.x;
  int b = bid >> 2, is = bid & 3;
  int t = threadIdx.x, w = t >> 6, lane = t & 63;
  int lm = lane & 15, lq = lane >> 4;
  const unsigned short* A = wsh + H_OWH + (size_t)(is * 64) * 128;     // out_w rows i
  const unsigned short* B = wsh + H_S2 + (size_t)b * 16384 + (size_t)(w * 32) * 128;  // S'' rows p
  f32x4 acc[4][2] = {};
  for (int k = 0; k < 128; k += 32) {
    bf16x8 a[4], bb[2];
#pragma unroll
    for (int i = 0; i < 4; ++i)
      a[i] = *(const bf16x8*)(A + (size_t)(i * 16 + lm) * 128 + lq * 8 + k);
#pragma unroll
    for (int j = 0; j < 2; ++j)
      bb[j] = *(const bf16x8*)(B + (size_t)(j * 16 + lm) * 128 + lq * 8 + k);
#pragma unroll
    for (int mi = 0; mi < 4; ++mi)
#pragma unroll
      for (int ni = 0; ni < 2; ++ni)
        acc[mi][ni] = __builtin_amdgcn_mfma_f32_16x16x32_bf16(a[mi], bb[ni], acc[mi][ni], 0, 0, 0);
  }
  const float inv = 1.0f / 4096.0f;
#pragma unroll
  for (int mi = 0; mi < 4; ++mi)
#pragma unroll
    for (int rr = 0; rr < 4; ++rr) {
      int i = is * 64 + mi * 16 + lq * 4 + rr;
#pragma unroll
      for (int ni = 0; ni < 2; ++ni) {
        int p = w * 32 + ni * 16 + lm;
        wsh[H_W2 + (size_t)b * 32768 + (size_t)i * 128 + p] = f2bf(acc[mi][ni][rr] * inv);
      }
    }
}

// ---- kD: LDS-free stream GEMM: out = x + W2 @ TT(_bt) + out_b. grid 512 ----
__global__ __launch_bounds__(256) void kD(const unsigned short* __restrict__ wsh,
                                          const float* __restrict__ x,
                                          const float* __restrict__ out_b,
                                          float* __restrict__ out) {
  int bid = blockIdx.x;
  int b = bid >> 7, r7 = bid & 127;
  int tm = r7 >> 6, tn = r7 & 63;
  int t = threadIdx.x, w = t >> 6, lane = t & 63;
  int wm = w >> 1, wn = w & 1;
  int lm = lane & 15, lq = lane >> 4;
  int rb = tm * 128 + wm * 64, cb = tn * 64 + wn * 32;
  const unsigned short* A = wsh + H_W2 + (size_t)b * 32768;
  const unsigned short* B = wsh + H_TT + (size_t)b * 524288;
  const unsigned short* ap[4];
  const unsigned short* bp[2];
#pragma unroll
  for (int i = 0; i < 4; ++i)
    ap[i] = A + (size_t)(rb + i * 16 + lm) * 128 + lq * 8;
#pragma unroll
  for (int j = 0; j < 2; ++j)
    bp[j] = B + (size_t)(cb + j * 16 + lm) * 128 + lq * 8;

  f32x4 acc[4][2] = {};
  bf16x8 a0[4], b0[2];
#pragma unroll
  for (int i = 0; i < 4; ++i) a0[i] = *(const bf16x8*)(ap[i]);
#pragma unroll
  for (int j = 0; j < 2; ++j) b0[j] = *(const bf16x8*)(bp[j]);
  for (int k = 32; k < 128; k += 32) {
    bf16x8 a1[4], b1[2];
#pragma unroll
    for (int i = 0; i < 4; ++i) a1[i] = *(const bf16x8*)(ap[i] + k);
#pragma unroll
    for (int j = 0; j < 2; ++j) b1[j] = *(const bf16x8*)(bp[j] + k);
#pragma unroll
    for (int mi = 0; mi < 4; ++mi)
#pragma unroll
      for (int ni = 0; ni < 2; ++ni)
        acc[mi][ni] = __builtin_amdgcn_mfma_f32_16x16x32_bf16(a0[mi], b0[ni], acc[mi][ni], 0, 0, 0);
#pragma unroll
    for (int i = 0; i < 4; ++i) a0[i] = a1[i];
#pragma unroll
    for (int j = 0; j < 2; ++j) b0[j] = b1[j];
  }
#pragma unroll
  for (int mi = 0; mi < 4; ++mi)
#pragma unroll
    for (int ni = 0; ni < 2; ++ni)
      acc[mi][ni] = __builtin_amdgcn_mfma_f32_16x16x32_bf16(a0[mi], b0[ni], acc[mi][ni], 0, 0, 0);

#pragma unroll
  for (int mi = 0; mi < 4; ++mi)
#pragma unroll
    for (int rr = 0; rr < 4; ++rr) {
      int row = rb + mi * 16 + lq * 4 + rr;
      float bi = out_b[row];
#pragma unroll
      for (int ni = 0; ni < 2; ++ni) {
        int col = cb + ni * 16 + lm;
        size_t off = ((size_t)b * CC + row) * NSP + col;
        out[off] = acc[mi][ni][rr] + x[off] + bi;
      }
    }
}

extern "C" void kernel_launch(void* const* d_in, const int* in_sizes, int n_in,
                              void* d_out, int out_size, void* d_ws, size_t ws_size,
                              hipStream_t stream) {
  const float* x       = (const float*)d_in[0];
  const float* g_w     = (const float*)d_in[1];
  const float* g_b     = (const float*)d_in[2];
  const float* theta_w = (const float*)d_in[3];
  const float* theta_b = (const float*)d_in[4];
  const float* phi_w   = (const float*)d_in[5];
  const float* phi_b   = (const float*)d_in[6];
  const float* out_w   = (const float*)d_in[7];
  const float* out_b   = (const float*)d_in[8];
  float* wsf = (float*)d_ws;
  unsigned short* wsh = (unsigned short*)(wsf + F_WEND);
  float* out = (float*)d_out;

  kW<<<dim3(128), dim3(256), 0, stream>>>(g_w, theta_w, phi_w, out_w, wsh);
  kP<<<dim3(512), dim3(256), 0, stream>>>(g_b, theta_b, phi_b, x, wsh);
  kS<<<dim3(64), dim3(256), 0, stream>>>(wsh, wsf);
  kR<<<dim3(64), dim3(256), 0, stream>>>(wsf, wsh);
  kW2<<<dim3(16), dim3(256), 0, stream>>>(wsh);
  kD<<<dim3(512), dim3(256), 0, stream>>>(wsh, x, out_b, out);
}